// Round 11
// baseline (472.097 us; speedup 1.0000x reference)
//
#include <hip/hip_runtime.h>
#include <hip/hip_bf16.h>

typedef __hip_bfloat16 bf16;
typedef __attribute__((ext_vector_type(8))) short short8_t;
typedef __attribute__((ext_vector_type(16))) float f32x16;
typedef __attribute__((ext_vector_type(2))) unsigned int uint2v;

#define HH 384
#define HW (384*384)
#define TOT_ELEMS (32u*4u*147456u)

__device__ inline float b2f(bf16 v){ return __bfloat162float(v); }
__device__ inline bf16  f2b(float v){ return __float2bfloat16(v); }
__device__ inline float sigm(float x){ return 1.f/(1.f+__expf(-x)); }

__device__ inline short8_t mk8p(uint2v a, uint2v b){
    union { uint u[4]; short8_t s; } t;
    t.u[0]=a[0]; t.u[1]=a[1]; t.u[2]=b[0]; t.u[3]=b[1]; return t.s;
}
__device__ inline uint ab2(uint h, uint l){ return __builtin_amdgcn_alignbyte(h, l, 2); }

// ---------------- K1: ci = sigmoid(pad1(conv3x3(inputs)+ic_b)), border = 0.5 ----------------
__global__ __launch_bounds__(256) void ci_kernel(const float* __restrict__ in,
                                                 const float* __restrict__ icw,
                                                 const float* __restrict__ icb,
                                                 bf16* __restrict__ ci)
{
    __shared__ float sw[108];
    __shared__ float sb[4];
    int tid = threadIdx.x;
    if (tid < 108) sw[tid] = icw[tid];
    if (tid < 4)   sb[tid] = icb[tid];
    __syncthreads();
    size_t idx = (size_t)blockIdx.x * 256 + tid;
    int x = (int)(idx % HH);
    int y = (int)((idx / HH) % HH);
    int b = (int)(idx / ((size_t)HH * HH));
    float v[4];
    if (y > 0 && y < HH-1 && x > 0 && x < HH-1) {
        float a0 = sb[0], a1 = sb[1], a2 = sb[2], a3 = sb[3];
        for (int ic = 0; ic < 3; ic++) {
            #pragma unroll
            for (int dy = 0; dy < 3; dy++) {
                #pragma unroll
                for (int dx = 0; dx < 3; dx++) {
                    float iv = in[((size_t)(b*3+ic)*HH + (y-1+dy))*HH + (x-1+dx)];
                    a0 = fmaf(iv, sw[0*27 + ic*9 + dy*3 + dx], a0);
                    a1 = fmaf(iv, sw[1*27 + ic*9 + dy*3 + dx], a1);
                    a2 = fmaf(iv, sw[2*27 + ic*9 + dy*3 + dx], a2);
                    a3 = fmaf(iv, sw[3*27 + ic*9 + dy*3 + dx], a3);
                }
            }
        }
        v[0]=sigm(a0); v[1]=sigm(a1); v[2]=sigm(a2); v[3]=sigm(a3);
    } else {
        v[0]=v[1]=v[2]=v[3]=0.5f;
    }
    #pragma unroll
    for (int o = 0; o < 4; o++)
        ci[((size_t)(b*4+o)*HH + y)*HH + x] = f2b(v[o]);
}

// ---------------- K2a: conv_feats ----------------
__global__ __launch_bounds__(256) void convfeats_kernel(const float* __restrict__ fm,
                                                        const float* __restrict__ mcw,
                                                        const float* __restrict__ mcb,
                                                        float* __restrict__ cf)
{
    __shared__ float sw[256*16];   // [c][k]
    int tid = threadIdx.x;
    int b = blockIdx.x >> 2, chunk = blockIdx.x & 3;
    for (int i = tid; i < 4096; i += 256) {
        int k = i / 256, c = i % 256;
        sw[c*16 + k] = mcw[k*256 + c];
    }
    __syncthreads();
    int hw = chunk*256 + tid;
    float acc[16];
    #pragma unroll
    for (int k = 0; k < 16; k++) acc[k] = mcb[k];
    const float* f = fm + (size_t)b*256*1024 + hw;
    for (int c = 0; c < 256; c++) {
        float v = f[(size_t)c*1024];
        const float4* wp = (const float4*)(sw + c*16);
        #pragma unroll
        for (int q = 0; q < 4; q++) {
            float4 t = wp[q];
            acc[q*4+0] = fmaf(v, t.x, acc[q*4+0]);
            acc[q*4+1] = fmaf(v, t.y, acc[q*4+1]);
            acc[q*4+2] = fmaf(v, t.z, acc[q*4+2]);
            acc[q*4+3] = fmaf(v, t.w, acc[q*4+3]);
        }
    }
    #pragma unroll
    for (int k = 0; k < 16; k++)
        cf[(size_t)b*16384 + k*1024 + hw] = acc[k];
}

// -------- K2c: wts = sigmoid((cf)@(meta@mlW.T+mlb)) -> bf16 [b][16][1024] --------
__global__ __launch_bounds__(256) void wts_kernel(const float* __restrict__ meta,
                                                  const float* __restrict__ mlw,
                                                  const float* __restrict__ mlb,
                                                  const float* __restrict__ cf,
                                                  bf16* __restrict__ wout)
{
    __shared__ float sm[64];
    __shared__ float sA[1024];
    __shared__ float sB[1024];
    int tid = threadIdx.x;
    int b = blockIdx.x >> 4, k = blockIdx.x & 15;
    if (tid < 64) sm[tid] = meta[(size_t)b*16*64 + k*64 + tid];
    #pragma unroll
    for (int q = 0; q < 4; q++)
        sA[q*256 + tid] = cf[(size_t)b*16384 + k*1024 + q*256 + tid];
    __syncthreads();
    #pragma unroll
    for (int q = 0; q < 4; q++) {
        int hw = q*256 + tid;
        const float4* wr = (const float4*)(mlw + (size_t)hw*64);
        float a = mlb[hw];
        #pragma unroll
        for (int d4 = 0; d4 < 16; d4++) {
            float4 t = wr[d4];
            a = fmaf(t.x, sm[d4*4+0], a);
            a = fmaf(t.y, sm[d4*4+1], a);
            a = fmaf(t.z, sm[d4*4+2], a);
            a = fmaf(t.w, sm[d4*4+3], a);
        }
        sB[hw] = a;
    }
    __syncthreads();
    #pragma unroll
    for (int q = 0; q < 4; q++) {
        int il = q*256 + tid;
        int i = il >> 5, l = il & 31;
        float a = 0.f;
        #pragma unroll
        for (int j = 0; j < 32; j++)
            a = fmaf(sA[i*32 + j], sB[j*32 + l], a);
        wout[(size_t)b*16384 + k*1024 + il] = f2b(sigm(a));
    }
}

// -------- A-fragment tables in MFMA lane order: [b][c][kyp][half][lane][8] --------
__global__ __launch_bounds__(256) void atab1F_kernel(const ushort* __restrict__ wts,
                                                     ushort* __restrict__ out)
{
    int g = blockIdx.x*256 + threadIdx.x;      // 32*4*39*2*64 = 638,976
    int lane = g & 63, half = (g >> 6) & 1;
    int rest = g >> 7;
    int kyp = rest % 39; int rest2 = rest / 39;
    int c = rest2 & 3, b = rest2 >> 2;
    int r = lane & 31, hi = lane >> 5;
    int dyA = r >> 2, mA = r & 3;
    int ch = mA*4 + c, ky = kyp - dyA, kx = 16*half + 8*hi;
    ushort v[8];
    if (ky >= 0 && ky < 32) {
        const ushort* src = wts + ((size_t)b*16 + ch)*1024 + ky*32 + kx;
        #pragma unroll
        for (int i=0;i<8;i++) v[i] = src[i];
    } else {
        #pragma unroll
        for (int i=0;i<8;i++) v[i] = 0;
    }
    __builtin_memcpy(out + (size_t)g*8, v, 16);
}

__global__ __launch_bounds__(256) void atab2F_kernel(const float* __restrict__ bbw,
                                                     ushort* __restrict__ out)
{
    int g = blockIdx.x*256 + threadIdx.x;      // 4*39*2*64 = 19,968
    int lane = g & 63, half = (g >> 6) & 1;
    int rest = g >> 7;
    int kyp = rest % 39;
    int c = rest / 39;
    int r = lane & 31, hi = lane >> 5;
    int dyA = r >> 2, mA = r & 3;
    int ch = mA*4 + c, ky = kyp - dyA, kx = 16*half + 8*hi;
    ushort v[8];
    if (ky >= 0 && ky < 32) {
        const float* src = bbw + (size_t)ch*1024 + ky*32 + kx;
        #pragma unroll
        for (int i=0;i<8;i++) { bf16 t = f2b(src[i]); v[i] = *(ushort*)&t; }
    } else {
        #pragma unroll
        for (int i=0;i<8;i++) v[i] = 0;
    }
    __builtin_memcpy(out + (size_t)g*8, v, 16);
}

// ================= quad-tile conv, dep-distance-ordered MFMAs, 2 waves/EU =================
// Block covers 32 output rows x 192 cols. Wave w: xs=(w&1)*96 (local), rowoff=(w>>1)*16.
// Per step: 12 x ds_read2_b32 (next step) -> s_waitcnt vmcnt lgkmcnt(12) -> 12 MFMA (cur),
// ordered so same-accumulator MFMAs are >=3 apart (hides matrix-pipe dependent latency).
#define G_LOADX4(dst, addr, OFF) \
    asm volatile("global_load_dwordx4 %0, %1, off offset:" OFF : "=v"(dst) : "v"(addr))

#define ISSUE_A(A0_, A1_, ap_, e_)                                   \
{                                                                    \
    const ushort* p_ = (ap_) + (unsigned)(e_)*1024u;                 \
    G_LOADX4(A0_, p_, "0");                                          \
    G_LOADX4(A1_, p_, "1024");                                       \
}

#define ISSUE_B(S, ADDR)                                                     \
    asm volatile(                                                            \
        "ds_read2_b32 %0, %12 offset0:0 offset1:1\n\t"                       \
        "ds_read2_b32 %1, %12 offset0:2 offset1:3\n\t"                       \
        "ds_read2_b32 %2, %12 offset0:8 offset1:9\n\t"                       \
        "ds_read2_b32 %3, %12 offset0:10 offset1:11\n\t"                     \
        "ds_read2_b32 %4, %12 offset0:16 offset1:17\n\t"                     \
        "ds_read2_b32 %5, %12 offset0:18 offset1:19\n\t"                     \
        "ds_read2_b32 %6, %12 offset0:24 offset1:25\n\t"                     \
        "ds_read2_b32 %7, %12 offset0:26 offset1:27\n\t"                     \
        "ds_read2_b32 %8, %12 offset0:32 offset1:33\n\t"                     \
        "ds_read2_b32 %9, %12 offset0:34 offset1:35\n\t"                     \
        "ds_read2_b32 %10, %12 offset0:40 offset1:41\n\t"                    \
        "ds_read2_b32 %11, %12 offset0:42 offset1:43"                        \
        : "=v"(S[0]), "=v"(S[1]), "=v"(S[2]), "=v"(S[3]), "=v"(S[4]),        \
          "=v"(S[5]), "=v"(S[6]), "=v"(S[7]), "=v"(S[8]), "=v"(S[9]),        \
          "=v"(S[10]), "=v"(S[11])                                           \
        : "v"(ADDR) : "memory")

#define KWAIT(VN, LN) do {                                                      \
    asm volatile("s_waitcnt vmcnt(" VN ") lgkmcnt(" LN ")" ::: "memory");       \
    __builtin_amdgcn_sched_barrier(0); } while (0)

#define MMp(acc_, A_, Pa, Pb) \
    acc_ = __builtin_amdgcn_mfma_f32_32x32x16_bf16(A_, mk8p(Pa, Pb), acc_, 0, 0, 0)

// T1-only: distance 3 between same-acc MFMAs
#define STEP1B(S, A0_, A1_, VN, LN) { KWAIT(VN, LN);                          \
    MMp(q0, A0_, S[0], S[1]);  MMp(q1, A0_, S[4], S[5]);                      \
    MMp(q2, A0_, S[8], S[9]);  MMp(q0, A1_, S[2], S[3]);                      \
    MMp(q1, A1_, S[6], S[7]);  MMp(q2, A1_, S[10], S[11]); }

#define STEP2B(S, C0_, C1_, VN, LN) { KWAIT(VN, LN);                          \
    MMp(u0, C0_, S[0], S[1]);  MMp(u1, C0_, S[4], S[5]);                      \
    MMp(u2, C0_, S[8], S[9]);  MMp(u0, C1_, S[2], S[3]);                      \
    MMp(u1, C1_, S[6], S[7]);  MMp(u2, C1_, S[10], S[11]); }

// both tiles: distance 6 between same-acc MFMAs; adjacent q/u pairs share a B quad
#define STEP12B(S, A0_, A1_, C0_, C1_, VN, LN) { KWAIT(VN, LN);               \
    MMp(q0, A0_, S[0], S[1]);   MMp(u0, C0_, S[0], S[1]);                     \
    MMp(q1, A0_, S[4], S[5]);   MMp(u1, C0_, S[4], S[5]);                     \
    MMp(q2, A0_, S[8], S[9]);   MMp(u2, C0_, S[8], S[9]);                     \
    MMp(q0, A1_, S[2], S[3]);   MMp(u0, C1_, S[2], S[3]);                     \
    MMp(q1, A1_, S[6], S[7]);   MMp(u1, C1_, S[6], S[7]);                     \
    MMp(q2, A1_, S[10], S[11]); MMp(u2, C1_, S[10], S[11]); }

template<bool PER_B, bool OUT_BF16, bool ADD_BIAS>
__global__ __launch_bounds__(256, 2) void conv32_quad(const ushort* __restrict__ in,
                                                      const ushort* __restrict__ atabF,
                                                      const float* __restrict__ bias,
                                                      void* __restrict__ outp)
{
    __shared__ uint sbuf[63*224];   // 56,448 B

    // XCD-chunk swizzle (768 % 8 == 0)
    int d = blockIdx.x;
    int chunkg = (int)gridDim.x >> 3;
    int L = (d & 7) * chunkg + (d >> 3);
    int b = L / 24; int rem = L % 24;
    int yb = rem >> 1, xb = rem & 1;
    int yv = yb * 32;
    int x0 = xb * 192;

    int tid = threadIdx.x;
    int l = tid & 63, w = tid >> 6;
    int rowoff = (w >> 1) * 16;        // row-group 0 / 16
    int xs = (w & 1) * 96;             // local x start within 192-col block
    int hi = l >> 5;

    int s = xs + (l & 31) + 8*hi;      // local start element (0..135)
    int p = s & 1;
    const uint* swl = sbuf + (unsigned)(rowoff*224) + (unsigned)(p*112 + ((s - p) >> 1));
    uint baddr0 = (uint)(size_t)(const void*)swl;   // LDS byte offset

    f32x16 q0, q1, q2, u0, u1, u2;
    #pragma unroll
    for (int i = 0; i < 16; i++) { q0[i]=0.f; q1[i]=0.f; q2[i]=0.f; u0[i]=0.f; u1[i]=0.f; u2[i]=0.f; }

    unsigned chbase0 = (unsigned)b*589824u + (unsigned)yv*384u + (unsigned)x0;

    for (int c = 0; c < 4; ++c) {
        if (c) __syncthreads();
        // ---- stage channel c: local rows 0..62 (image rows yv..yv+62), 224 elems + parity copy ----
        unsigned chb = chbase0 + (unsigned)c*147456u;
        for (int qq = tid; qq < 1764; qq += 256) {     // 63 rows * 28 chunks of 8 el
            int row = qq / 28, k = qq - row*28;
            unsigned gi = chb + (unsigned)row*384u + (unsigned)k*8u;
            if (gi > TOT_ELEMS - 16u) gi = TOT_ELEMS - 16u;
            const uint* gp = (const uint*)(in + gi);   // 16B aligned
            uint d0 = gp[0], d1 = gp[1], d2 = gp[2], d3 = gp[3], d4 = gp[4];
            unsigned widx = (unsigned)row*224u + (unsigned)k*4u;
            uint4* w0 = (uint4*)&sbuf[widx];
            uint4* w1 = (uint4*)&sbuf[widx + 112u];
            *w0 = make_uint4(d0, d1, d2, d3);
            *w1 = make_uint4(ab2(d1,d0), ab2(d2,d1), ab2(d3,d2), ab2(d4,d3));
        }
        __syncthreads();

        const ushort* ap1 = atabF + (size_t)((PER_B ? (b*4 + c) : c) * 39) * 1024 + l*8;
        short8_t xA0, xA1, yA0, yA1;      // T1 A pipeline
        short8_t x20, x21, y20, y21;      // T2 A pipeline
        uint2v sE[12], sO[12];            // B double buffer
        uint baddr = baddr0;

        ISSUE_B(sE, baddr); baddr += 896u;
        ISSUE_A(xA0, xA1, ap1, 0);

        // ---- P1: steps 0..7, T1 only ----
        ISSUE_B(sO, baddr); baddr += 896u;
        ISSUE_A(yA0, yA1, ap1, 1);
        STEP1B(sE, xA0, xA1, "2", "12");
        ISSUE_B(sE, baddr); baddr += 896u;
        ISSUE_A(xA0, xA1, ap1, 2);
        STEP1B(sO, yA0, yA1, "2", "12");
        ISSUE_B(sO, baddr); baddr += 896u;
        ISSUE_A(yA0, yA1, ap1, 3);
        STEP1B(sE, xA0, xA1, "2", "12");
        ISSUE_B(sE, baddr); baddr += 896u;
        ISSUE_A(xA0, xA1, ap1, 4);
        STEP1B(sO, yA0, yA1, "2", "12");
        ISSUE_B(sO, baddr); baddr += 896u;
        ISSUE_A(yA0, yA1, ap1, 5);
        STEP1B(sE, xA0, xA1, "2", "12");
        ISSUE_B(sE, baddr); baddr += 896u;
        ISSUE_A(xA0, xA1, ap1, 6);
        STEP1B(sO, yA0, yA1, "2", "12");
        ISSUE_B(sO, baddr); baddr += 896u;
        ISSUE_A(yA0, yA1, ap1, 7);
        STEP1B(sE, xA0, xA1, "2", "12");
        ISSUE_B(sE, baddr); baddr += 896u;
        ISSUE_A(xA0, xA1, ap1, 8);
        ISSUE_A(x20, x21, ap1, 0);
        STEP1B(sO, yA0, yA1, "4", "12");

        // ---- P2: steps 8..37, both tiles (T1 entry r, T2 entry r-8) ----
        #pragma unroll 1
        for (int t = 0; t < 15; ++t) {
            int r = 8 + 2*t;
            ISSUE_B(sO, baddr); baddr += 896u;
            ISSUE_A(yA0, yA1, ap1, r+1); ISSUE_A(y20, y21, ap1, r-7);
            STEP12B(sE, xA0, xA1, x20, x21, "4", "12");
            ISSUE_B(sE, baddr); baddr += 896u;
            ISSUE_A(xA0, xA1, ap1, r+2); ISSUE_A(x20, x21, ap1, r-6);
            STEP12B(sO, yA0, yA1, y20, y21, "4", "12");
        }
        // ---- step 38 ----
        ISSUE_B(sO, baddr); baddr += 896u;
        ISSUE_A(y20, y21, ap1, 31);
        STEP12B(sE, xA0, xA1, x20, x21, "2", "12");

        // ---- P3: steps 39..46, T2 only (entries 31..38) ----
        ISSUE_B(sE, baddr); baddr += 896u; ISSUE_A(x20, x21, ap1, 32); STEP2B(sO, y20, y21, "2", "12");
        ISSUE_B(sO, baddr); baddr += 896u; ISSUE_A(y20, y21, ap1, 33); STEP2B(sE, x20, x21, "2", "12");
        ISSUE_B(sE, baddr); baddr += 896u; ISSUE_A(x20, x21, ap1, 34); STEP2B(sO, y20, y21, "2", "12");
        ISSUE_B(sO, baddr); baddr += 896u; ISSUE_A(y20, y21, ap1, 35); STEP2B(sE, x20, x21, "2", "12");
        ISSUE_B(sE, baddr); baddr += 896u; ISSUE_A(x20, x21, ap1, 36); STEP2B(sO, y20, y21, "2", "12");
        ISSUE_B(sO, baddr); baddr += 896u; ISSUE_A(y20, y21, ap1, 37); STEP2B(sE, x20, x21, "2", "12");
        ISSUE_B(sE, baddr); baddr += 896u; ISSUE_A(x20, x21, ap1, 38); STEP2B(sO, y20, y21, "2", "12");
        STEP2B(sE, x20, x21, "0", "0");
    }

    float bv0 = 0.f, bv1 = 0.f, bv2 = 0.f, bv3 = 0.f;
    if (ADD_BIAS) { bv0 = bias[0]; bv1 = bias[1]; bv2 = bias[2]; bv3 = bias[3]; }

    #pragma unroll
    for (int j = 0; j < 3; j++) {
        int ox = x0 + xs + 32*j + (l & 31);
        if (ox > 352) continue;
        int px = ox + 15;
        #pragma unroll
        for (int rg = 0; rg < 16; rg++) {
            int m  = rg & 3;
            int dy = 2*(rg >> 2) + hi;
            float v1 = (j == 0 ? q0[rg] : (j == 1 ? q1[rg] : q2[rg]));
            float v2 = (j == 0 ? u0[rg] : (j == 1 ? u1[rg] : u2[rg]));
            float bb = (m == 0 ? bv0 : m == 1 ? bv1 : m == 2 ? bv2 : bv3);
            int oy1 = yv + rowoff + dy;
            if (oy1 <= 352) {
                size_t o = ((size_t)(b*4 + m))*HW + (size_t)(oy1 + 15)*HH + px;
                float v = v1 + (ADD_BIAS ? bb : 0.f);
                if constexpr (OUT_BF16) ((bf16*)outp)[o] = f2b(v);
                else                    ((float*)outp)[o] = v;
            }
            int oy2 = yv + rowoff + 8 + dy;
            if (oy2 <= 352) {
                size_t o = ((size_t)(b*4 + m))*HW + (size_t)(oy2 + 15)*HH + px;
                float v = v2 + (ADD_BIAS ? bb : 0.f);
                if constexpr (OUT_BF16) ((bf16*)outp)[o] = f2b(v);
                else                    ((float*)outp)[o] = v;
            }
        }
    }
}

extern "C" void kernel_launch(void* const* d_in, const int* in_sizes, int n_in,
                              void* d_out, int out_size, void* d_ws, size_t ws_size,
                              hipStream_t stream)
{
    const float* inputs = (const float*)d_in[0];
    const float* fm     = (const float*)d_in[1];
    const float* meta   = (const float*)d_in[2];
    const float* mcw    = (const float*)d_in[3];
    const float* mcb    = (const float*)d_in[4];
    const float* mlw    = (const float*)d_in[5];
    const float* mlb    = (const float*)d_in[6];
    const float* icw    = (const float*)d_in[7];
    const float* icb    = (const float*)d_in[8];
    const float* bbw    = (const float*)d_in[9];
    const float* bbb    = (const float*)d_in[10];

    // workspace layout (bytes):
    //   ci     bf16 [32,4,384,384]      @ 0           37,748,736
    //   mapped bf16 [32,4,384,384]      @ 37,748,736  37,748,736
    //   cf     f32  [32,16,1024]        @ 75,497,472   2,097,152
    //   wts    bf16 [32,16,1024]        @ 77,594,624   1,048,576
    //   atab1F bf16 [32,4,39,2,64,8]    @ 78,643,200  10,223,616
    //   atab2F bf16 [4,39,2,64,8]       @ 88,866,816     319,488
    char* ws = (char*)d_ws;
    bf16*   ci     = (bf16*) ws;
    bf16*   mapped = (bf16*)(ws + 37748736);
    float*  cf     = (float*)(ws + 75497472);
    bf16*   wts    = (bf16*)(ws + 77594624);
    ushort* atab1F = (ushort*)(ws + 78643200);
    ushort* atab2F = (ushort*)(ws + 88866816);

    ci_kernel<<<18432, 256, 0, stream>>>(inputs, icw, icb, ci);
    convfeats_kernel<<<128, 256, 0, stream>>>(fm, mcw, mcb, cf);
    wts_kernel<<<512, 256, 0, stream>>>(meta, mlw, mlb, cf, wts);
    atab1F_kernel<<<2496, 256, 0, stream>>>((const ushort*)wts, atab1F);
    atab2F_kernel<<<78, 256, 0, stream>>>(bbw, atab2F);

    hipMemsetAsync(mapped, 0, 37748736, stream);
    conv32_quad<true, true, false><<<768, 256, 0, stream>>>(
        (const ushort*)ci, atab1F, nullptr, mapped);

    hipMemsetAsync(d_out, 0, (size_t)out_size * 4, stream);
    conv32_quad<false, false, true><<<768, 256, 0, stream>>>(
        (const ushort*)mapped, atab2F, bbb, d_out);
}

// Round 15
// 446.685 us; speedup vs baseline: 1.0569x; 1.0569x over previous
//
#include <hip/hip_runtime.h>
#include <hip/hip_bf16.h>

typedef __hip_bfloat16 bf16;
typedef __attribute__((ext_vector_type(8))) short short8_t;
typedef __attribute__((ext_vector_type(16))) float f32x16;
typedef __attribute__((ext_vector_type(2))) unsigned int uint2v;

#define HH 384
#define HW (384*384)
#define TOT_ELEMS (32u*4u*147456u)

__device__ inline float b2f(bf16 v){ return __bfloat162float(v); }
__device__ inline bf16  f2b(float v){ return __float2bfloat16(v); }
__device__ inline float sigm(float x){ return 1.f/(1.f+__expf(-x)); }

__device__ inline uint ab2(uint h, uint l){ return __builtin_amdgcn_alignbyte(h, l, 2); }

__device__ inline short8_t mk8p(uint2v a, uint2v b){
    union { uint u[4]; short8_t s; } t;
    t.u[0]=a[0]; t.u[1]=a[1]; t.u[2]=b[0]; t.u[3]=b[1]; return t.s;
}

// ---------------- K1: ci = sigmoid(pad1(conv3x3(inputs)+ic_b)), border = 0.5 ----------------
__global__ __launch_bounds__(256) void ci_kernel(const float* __restrict__ in,
                                                 const float* __restrict__ icw,
                                                 const float* __restrict__ icb,
                                                 bf16* __restrict__ ci)
{
    __shared__ float sw[108];
    __shared__ float sb[4];
    int tid = threadIdx.x;
    if (tid < 108) sw[tid] = icw[tid];
    if (tid < 4)   sb[tid] = icb[tid];
    __syncthreads();
    size_t idx = (size_t)blockIdx.x * 256 + tid;
    int x = (int)(idx % HH);
    int y = (int)((idx / HH) % HH);
    int b = (int)(idx / ((size_t)HH * HH));
    float v[4];
    if (y > 0 && y < HH-1 && x > 0 && x < HH-1) {
        float a0 = sb[0], a1 = sb[1], a2 = sb[2], a3 = sb[3];
        for (int ic = 0; ic < 3; ic++) {
            #pragma unroll
            for (int dy = 0; dy < 3; dy++) {
                #pragma unroll
                for (int dx = 0; dx < 3; dx++) {
                    float iv = in[((size_t)(b*3+ic)*HH + (y-1+dy))*HH + (x-1+dx)];
                    a0 = fmaf(iv, sw[0*27 + ic*9 + dy*3 + dx], a0);
                    a1 = fmaf(iv, sw[1*27 + ic*9 + dy*3 + dx], a1);
                    a2 = fmaf(iv, sw[2*27 + ic*9 + dy*3 + dx], a2);
                    a3 = fmaf(iv, sw[3*27 + ic*9 + dy*3 + dx], a3);
                }
            }
        }
        v[0]=sigm(a0); v[1]=sigm(a1); v[2]=sigm(a2); v[3]=sigm(a3);
    } else {
        v[0]=v[1]=v[2]=v[3]=0.5f;
    }
    #pragma unroll
    for (int o = 0; o < 4; o++)
        ci[((size_t)(b*4+o)*HH + y)*HH + x] = f2b(v[o]);
}

// ---------------- K2a: conv_feats ----------------
__global__ __launch_bounds__(256) void convfeats_kernel(const float* __restrict__ fm,
                                                        const float* __restrict__ mcw,
                                                        const float* __restrict__ mcb,
                                                        float* __restrict__ cf)
{
    __shared__ float sw[256*16];   // [c][k]
    int tid = threadIdx.x;
    int b = blockIdx.x >> 2, chunk = blockIdx.x & 3;
    for (int i = tid; i < 4096; i += 256) {
        int k = i / 256, c = i % 256;
        sw[c*16 + k] = mcw[k*256 + c];
    }
    __syncthreads();
    int hw = chunk*256 + tid;
    float acc[16];
    #pragma unroll
    for (int k = 0; k < 16; k++) acc[k] = mcb[k];
    const float* f = fm + (size_t)b*256*1024 + hw;
    for (int c = 0; c < 256; c++) {
        float v = f[(size_t)c*1024];
        const float4* wp = (const float4*)(sw + c*16);
        #pragma unroll
        for (int q = 0; q < 4; q++) {
            float4 t = wp[q];
            acc[q*4+0] = fmaf(v, t.x, acc[q*4+0]);
            acc[q*4+1] = fmaf(v, t.y, acc[q*4+1]);
            acc[q*4+2] = fmaf(v, t.z, acc[q*4+2]);
            acc[q*4+3] = fmaf(v, t.w, acc[q*4+3]);
        }
    }
    #pragma unroll
    for (int k = 0; k < 16; k++)
        cf[(size_t)b*16384 + k*1024 + hw] = acc[k];
}

// -------- K2c: wts = sigmoid((cf)@(meta@mlW.T+mlb)) -> bf16 [b][16][1024] --------
__global__ __launch_bounds__(256) void wts_kernel(const float* __restrict__ meta,
                                                  const float* __restrict__ mlw,
                                                  const float* __restrict__ mlb,
                                                  const float* __restrict__ cf,
                                                  bf16* __restrict__ wout)
{
    __shared__ float sm[64];
    __shared__ float sA[1024];
    __shared__ float sB[1024];
    int tid = threadIdx.x;
    int b = blockIdx.x >> 4, k = blockIdx.x & 15;
    if (tid < 64) sm[tid] = meta[(size_t)b*16*64 + k*64 + tid];
    #pragma unroll
    for (int q = 0; q < 4; q++)
        sA[q*256 + tid] = cf[(size_t)b*16384 + k*1024 + q*256 + tid];
    __syncthreads();
    #pragma unroll
    for (int q = 0; q < 4; q++) {
        int hw = q*256 + tid;
        const float4* wr = (const float4*)(mlw + (size_t)hw*64);
        float a = mlb[hw];
        #pragma unroll
        for (int d4 = 0; d4 < 16; d4++) {
            float4 t = wr[d4];
            a = fmaf(t.x, sm[d4*4+0], a);
            a = fmaf(t.y, sm[d4*4+1], a);
            a = fmaf(t.z, sm[d4*4+2], a);
            a = fmaf(t.w, sm[d4*4+3], a);
        }
        sB[hw] = a;
    }
    __syncthreads();
    #pragma unroll
    for (int q = 0; q < 4; q++) {
        int il = q*256 + tid;
        int i = il >> 5, l = il & 31;
        float a = 0.f;
        #pragma unroll
        for (int j = 0; j < 32; j++)
            a = fmaf(sA[i*32 + j], sB[j*32 + l], a);
        wout[(size_t)b*16384 + k*1024 + il] = f2b(sigm(a));
    }
}

// -------- A-fragment tables in MFMA lane order: [b][c][kyp][half][lane][8] --------
__global__ __launch_bounds__(256) void atab1F_kernel(const ushort* __restrict__ wts,
                                                     ushort* __restrict__ out)
{
    int g = blockIdx.x*256 + threadIdx.x;      // 32*4*39*2*64 = 638,976
    int lane = g & 63, half = (g >> 6) & 1;
    int rest = g >> 7;
    int kyp = rest % 39; int rest2 = rest / 39;
    int c = rest2 & 3, b = rest2 >> 2;
    int r = lane & 31, hi = lane >> 5;
    int dyA = r >> 2, mA = r & 3;
    int ch = mA*4 + c, ky = kyp - dyA, kx = 16*half + 8*hi;
    ushort v[8];
    if (ky >= 0 && ky < 32) {
        const ushort* src = wts + ((size_t)b*16 + ch)*1024 + ky*32 + kx;
        #pragma unroll
        for (int i=0;i<8;i++) v[i] = src[i];
    } else {
        #pragma unroll
        for (int i=0;i<8;i++) v[i] = 0;
    }
    __builtin_memcpy(out + (size_t)g*8, v, 16);
}

__global__ __launch_bounds__(256) void atab2F_kernel(const float* __restrict__ bbw,
                                                     ushort* __restrict__ out)
{
    int g = blockIdx.x*256 + threadIdx.x;      // 4*39*2*64 = 19,968
    int lane = g & 63, half = (g >> 6) & 1;
    int rest = g >> 7;
    int kyp = rest % 39;
    int c = rest / 39;
    int r = lane & 31, hi = lane >> 5;
    int dyA = r >> 2, mA = r & 3;
    int ch = mA*4 + c, ky = kyp - dyA, kx = 16*half + 8*hi;
    ushort v[8];
    if (ky >= 0 && ky < 32) {
        const float* src = bbw + (size_t)ch*1024 + ky*32 + kx;
        #pragma unroll
        for (int i=0;i<8;i++) { bf16 t = f2b(src[i]); v[i] = *(ushort*)&t; }
    } else {
        #pragma unroll
        for (int i=0;i<8;i++) v[i] = 0;
    }
    __builtin_memcpy(out + (size_t)g*8, v, 16);
}

// ================= duo-tile conv, 64-col waves, 3 waves/SIMD occupancy =================
// Wave: 16 out rows x 64 cols (T1 rows +0..7, T2 +8..15; 2 col strips). Block = 4 waves
// = 2 row-groups (0/16) x 2 x-strips (0/64) -> 32 rows x 128 cols. 47 steps/channel.
// LDS: 63 rows x 160 words (copy0 80 | copy1 80, bank-shift 16) = 40,320 B -> 3 blocks/CU.
// NOTE: no s_setprio anywhere (A/B vs round 14 — isolating the correctness failure).
#define G_LOADX4(dst, addr, OFF) \
    asm volatile("global_load_dwordx4 %0, %1, off offset:" OFF : "=v"(dst) : "v"(addr))

#define ISSUE_A(A0_, A1_, ap_, e_)                                   \
{                                                                    \
    const ushort* p_ = (ap_) + (unsigned)(e_)*1024u;                 \
    G_LOADX4(A0_, p_, "0");                                          \
    G_LOADX4(A1_, p_, "1024");                                       \
}

#define ISSUE_B8(S, ADDR)                                                    \
    asm volatile(                                                            \
        "ds_read2_b32 %0, %8 offset0:0 offset1:1\n\t"                        \
        "ds_read2_b32 %1, %8 offset0:2 offset1:3\n\t"                        \
        "ds_read2_b32 %2, %8 offset0:8 offset1:9\n\t"                        \
        "ds_read2_b32 %3, %8 offset0:10 offset1:11\n\t"                      \
        "ds_read2_b32 %4, %8 offset0:16 offset1:17\n\t"                      \
        "ds_read2_b32 %5, %8 offset0:18 offset1:19\n\t"                      \
        "ds_read2_b32 %6, %8 offset0:24 offset1:25\n\t"                      \
        "ds_read2_b32 %7, %8 offset0:26 offset1:27"                          \
        : "=v"(S[0]), "=v"(S[1]), "=v"(S[2]), "=v"(S[3]), "=v"(S[4]),        \
          "=v"(S[5]), "=v"(S[6]), "=v"(S[7])                                 \
        : "v"(ADDR) : "memory")

#define KWAIT(VN, LN) do {                                                      \
    asm volatile("s_waitcnt vmcnt(" VN ") lgkmcnt(" LN ")" ::: "memory");       \
    __builtin_amdgcn_sched_barrier(0); } while (0)

#define MMp(acc_, A_, Pa, Pb) \
    acc_ = __builtin_amdgcn_mfma_f32_32x32x16_bf16(A_, mk8p(Pa, Pb), acc_, 0, 0, 0)

// T1-only: 4 MFMA (2 strips x 2 K-halves), same-acc distance 2
#define STEP1B(S, A0_, A1_, VN, LN) { KWAIT(VN, LN);                          \
    MMp(q0, A0_, S[0], S[1]);  MMp(q1, A0_, S[4], S[5]);                      \
    MMp(q0, A1_, S[2], S[3]);  MMp(q1, A1_, S[6], S[7]); }

#define STEP2B(S, C0_, C1_, VN, LN) { KWAIT(VN, LN);                          \
    MMp(u0, C0_, S[0], S[1]);  MMp(u1, C0_, S[4], S[5]);                      \
    MMp(u0, C1_, S[2], S[3]);  MMp(u1, C1_, S[6], S[7]); }

// both tiles: 8 MFMA, same-acc distance 4; q/u pairs share a B quad
#define STEP12B(S, A0_, A1_, C0_, C1_, VN, LN) { KWAIT(VN, LN);               \
    MMp(q0, A0_, S[0], S[1]);   MMp(u0, C0_, S[0], S[1]);                     \
    MMp(q1, A0_, S[4], S[5]);   MMp(u1, C0_, S[4], S[5]);                     \
    MMp(q0, A1_, S[2], S[3]);   MMp(u0, C1_, S[2], S[3]);                     \
    MMp(q1, A1_, S[6], S[7]);   MMp(u1, C1_, S[6], S[7]); }

template<bool PER_B, bool OUT_BF16, bool ADD_BIAS>
__global__ __launch_bounds__(256, 3) void conv32_duo(const ushort* __restrict__ in,
                                                     const ushort* __restrict__ atabF,
                                                     const float* __restrict__ bias,
                                                     void* __restrict__ outp)
{
    __shared__ uint sbuf[63*160];   // 40,320 B

    // XCD-chunk swizzle (1152 % 8 == 0)
    int d = blockIdx.x;
    int L = (d & 7) * 144 + (d >> 3);
    int b = L / 36; int rem = L % 36;
    int yb = rem / 3, xb = rem % 3;
    int yv = yb * 32;
    int x0 = xb * 128;

    int tid = threadIdx.x;
    int l = tid & 63, w = tid >> 6;
    int rg = (w >> 1) * 16;            // row-group 0 / 16
    int xs = (w & 1) * 64;             // local x start within 128-col block
    int hi = l >> 5;

    int s = xs + (l & 31) + 8*hi;      // local start element (0..103)
    int p = s & 1;
    const uint* swl = sbuf + (unsigned)(rg*160) + (unsigned)(p*80 + ((s - p) >> 1));
    uint baddr0 = (uint)(size_t)(const void*)swl;   // LDS byte offset

    f32x16 q0, q1, u0, u1;
    #pragma unroll
    for (int i = 0; i < 16; i++) { q0[i]=0.f; q1[i]=0.f; u0[i]=0.f; u1[i]=0.f; }

    unsigned chbase0 = (unsigned)b*589824u + (unsigned)yv*384u + (unsigned)x0;

    for (int c = 0; c < 4; ++c) {
        if (c) __syncthreads();
        // ---- stage channel c: local rows 0..62 (image rows yv..yv+62), 160 el + parity copy ----
        unsigned chb = chbase0 + (unsigned)c*147456u;
        for (int qq = tid; qq < 1260; qq += 256) {     // 63 rows * 20 chunks of 8 el
            int row = qq / 20, k = qq - row*20;
            unsigned gi = chb + (unsigned)row*384u + (unsigned)k*8u;
            if (gi > TOT_ELEMS - 16u) gi = TOT_ELEMS - 16u;
            const uint* gp = (const uint*)(in + gi);   // 16B aligned
            uint d0 = gp[0], d1 = gp[1], d2 = gp[2], d3 = gp[3], d4 = gp[4];
            unsigned widx = (unsigned)row*160u + (unsigned)k*4u;
            uint4* w0 = (uint4*)&sbuf[widx];
            uint4* w1 = (uint4*)&sbuf[widx + 80u];
            *w0 = make_uint4(d0, d1, d2, d3);
            *w1 = make_uint4(ab2(d1,d0), ab2(d2,d1), ab2(d3,d2), ab2(d4,d3));
        }
        __syncthreads();

        const ushort* ap1 = atabF + (size_t)((PER_B ? (b*4 + c) : c) * 39) * 1024 + l*8;
        short8_t xA0, xA1, yA0, yA1;      // T1 A pipeline
        short8_t x20, x21, y20, y21;      // T2 A pipeline
        uint2v sE[8], sO[8];              // B double buffer
        uint baddr = baddr0;

        ISSUE_B8(sE, baddr); baddr += 640u;
        ISSUE_A(xA0, xA1, ap1, 0);

        // ---- P1: steps 0..7, T1 only ----
        ISSUE_B8(sO, baddr); baddr += 640u;
        ISSUE_A(yA0, yA1, ap1, 1);
        STEP1B(sE, xA0, xA1, "2", "8");
        ISSUE_B8(sE, baddr); baddr += 640u;
        ISSUE_A(xA0, xA1, ap1, 2);
        STEP1B(sO, yA0, yA1, "2", "8");
        ISSUE_B8(sO, baddr); baddr += 640u;
        ISSUE_A(yA0, yA1, ap1, 3);
        STEP1B(sE, xA0, xA1, "2", "8");
        ISSUE_B8(sE, baddr); baddr += 640u;
        ISSUE_A(xA0, xA1, ap1, 4);
        STEP1B(sO, yA0, yA1, "2", "8");
        ISSUE_B8(sO, baddr); baddr += 640u;
        ISSUE_A(yA0, yA1, ap1, 5);
        STEP1B(sE, xA0, xA1, "2", "8");
        ISSUE_B8(sE, baddr); baddr += 640u;
        ISSUE_A(xA0, xA1, ap1, 6);
        STEP1B(sO, yA0, yA1, "2", "8");
        ISSUE_B8(sO, baddr); baddr += 640u;
        ISSUE_A(yA0, yA1, ap1, 7);
        STEP1B(sE, xA0, xA1, "2", "8");
        ISSUE_B8(sE, baddr); baddr += 640u;
        ISSUE_A(xA0, xA1, ap1, 8);
        ISSUE_A(x20, x21, ap1, 0);
        STEP1B(sO, yA0, yA1, "4", "8");

        // ---- P2: steps 8..37, both tiles (T1 entry r, T2 entry r-8) ----
        #pragma unroll 1
        for (int t = 0; t < 15; ++t) {
            int r = 8 + 2*t;
            ISSUE_B8(sO, baddr); baddr += 640u;
            ISSUE_A(yA0, yA1, ap1, r+1); ISSUE_A(y20, y21, ap1, r-7);
            STEP12B(sE, xA0, xA1, x20, x21, "4", "8");
            ISSUE_B8(sE, baddr); baddr += 640u;
            ISSUE_A(xA0, xA1, ap1, r+2); ISSUE_A(x20, x21, ap1, r-6);
            STEP12B(sO, yA0, yA1, y20, y21, "4", "8");
        }
        // ---- step 38 ----
        ISSUE_B8(sO, baddr); baddr += 640u;
        ISSUE_A(y20, y21, ap1, 31);
        STEP12B(sE, xA0, xA1, x20, x21, "2", "8");

        // ---- P3: steps 39..46, T2 only (entries 31..38) ----
        ISSUE_B8(sE, baddr); baddr += 640u; ISSUE_A(x20, x21, ap1, 32); STEP2B(sO, y20, y21, "2", "8");
        ISSUE_B8(sO, baddr); baddr += 640u; ISSUE_A(y20, y21, ap1, 33); STEP2B(sE, x20, x21, "2", "8");
        ISSUE_B8(sE, baddr); baddr += 640u; ISSUE_A(x20, x21, ap1, 34); STEP2B(sO, y20, y21, "2", "8");
        ISSUE_B8(sO, baddr); baddr += 640u; ISSUE_A(y20, y21, ap1, 35); STEP2B(sE, x20, x21, "2", "8");
        ISSUE_B8(sE, baddr); baddr += 640u; ISSUE_A(x20, x21, ap1, 36); STEP2B(sO, y20, y21, "2", "8");
        ISSUE_B8(sO, baddr); baddr += 640u; ISSUE_A(y20, y21, ap1, 37); STEP2B(sE, x20, x21, "2", "8");
        ISSUE_B8(sE, baddr); baddr += 640u; ISSUE_A(x20, x21, ap1, 38); STEP2B(sO, y20, y21, "2", "8");
        STEP2B(sE, x20, x21, "0", "0");
    }

    float bv0 = 0.f, bv1 = 0.f, bv2 = 0.f, bv3 = 0.f;
    if (ADD_BIAS) { bv0 = bias[0]; bv1 = bias[1]; bv2 = bias[2]; bv3 = bias[3]; }

    #pragma unroll
    for (int j = 0; j < 2; j++) {
        int ox = x0 + xs + 32*j + (l & 31);
        if (ox > 352) continue;
        int px = ox + 15;
        #pragma unroll
        for (int rgi = 0; rgi < 16; rgi++) {
            int m  = rgi & 3;
            int dy = 2*(rgi >> 2) + hi;
            float v1 = (j == 0 ? q0[rgi] : q1[rgi]);
            float v2 = (j == 0 ? u0[rgi] : u1[rgi]);
            float bb = (m == 0 ? bv0 : m == 1 ? bv1 : m == 2 ? bv2 : bv3);
            int oy1 = yv + rg + dy;
            if (oy1 <= 352) {
                size_t o = ((size_t)(b*4 + m))*HW + (size_t)(oy1 + 15)*HH + px;
                float v = v1 + (ADD_BIAS ? bb : 0.f);
                if constexpr (OUT_BF16) ((bf16*)outp)[o] = f2b(v);
                else                    ((float*)outp)[o] = v;
            }
            int oy2 = yv + rg + 8 + dy;
            if (oy2 <= 352) {
                size_t o = ((size_t)(b*4 + m))*HW + (size_t)(oy2 + 15)*HH + px;
                float v = v2 + (ADD_BIAS ? bb : 0.f);
                if constexpr (OUT_BF16) ((bf16*)outp)[o] = f2b(v);
                else                    ((float*)outp)[o] = v;
            }
        }
    }
}

extern "C" void kernel_launch(void* const* d_in, const int* in_sizes, int n_in,
                              void* d_out, int out_size, void* d_ws, size_t ws_size,
                              hipStream_t stream)
{
    const float* inputs = (const float*)d_in[0];
    const float* fm     = (const float*)d_in[1];
    const float* meta   = (const float*)d_in[2];
    const float* mcw    = (const float*)d_in[3];
    const float* mcb    = (const float*)d_in[4];
    const float* mlw    = (const float*)d_in[5];
    const float* mlb    = (const float*)d_in[6];
    const float* icw    = (const float*)d_in[7];
    const float* icb    = (const float*)d_in[8];
    const float* bbw    = (const float*)d_in[9];
    const float* bbb    = (const float*)d_in[10];

    // workspace layout (bytes):
    //   ci     bf16 [32,4,384,384]      @ 0           37,748,736
    //   mapped bf16 [32,4,384,384]      @ 37,748,736  37,748,736
    //   cf     f32  [32,16,1024]        @ 75,497,472   2,097,152
    //   wts    bf16 [32,16,1024]        @ 77,594,624   1,048,576
    //   atab1F bf16 [32,4,39,2,64,8]    @ 78,643,200  10,223,616
    //   atab2F bf16 [4,39,2,64,8]       @ 88,866,816     319,488
    char* ws = (char*)d_ws;
    bf16*   ci     = (bf16*) ws;
    bf16*   mapped = (bf16*)(ws + 37748736);
    float*  cf     = (float*)(ws + 75497472);
    bf16*   wts    = (bf16*)(ws + 77594624);
    ushort* atab1F = (ushort*)(ws + 78643200);
    ushort* atab2F = (ushort*)(ws + 88866816);

    ci_kernel<<<18432, 256, 0, stream>>>(inputs, icw, icb, ci);
    convfeats_kernel<<<128, 256, 0, stream>>>(fm, mcw, mcb, cf);
    wts_kernel<<<512, 256, 0, stream>>>(meta, mlw, mlb, cf, wts);
    atab1F_kernel<<<2496, 256, 0, stream>>>((const ushort*)wts, atab1F);
    atab2F_kernel<<<78, 256, 0, stream>>>(bbw, atab2F);

    hipMemsetAsync(mapped, 0, 37748736, stream);
    conv32_duo<true, true, false><<<1152, 256, 0, stream>>>(
        (const ushort*)ci, atab1F, nullptr, mapped);

    hipMemsetAsync(d_out, 0, (size_t)out_size * 4, stream);
    conv32_duo<false, false, true><<<1152, 256, 0, stream>>>(
        (const ushort*)mapped, atab2F, bbb, d_out);
}

// Round 19
// 412.644 us; speedup vs baseline: 1.1441x; 1.0825x over previous
//
#include <hip/hip_runtime.h>
#include <hip/hip_bf16.h>

typedef __hip_bfloat16 bf16;
typedef __attribute__((ext_vector_type(8))) short short8_t;
typedef __attribute__((ext_vector_type(16))) float f32x16;
typedef __attribute__((ext_vector_type(2))) unsigned int uint2v;

#define HH 384
#define HW (384*384)
#define TOT_ELEMS (32u*4u*147456u)
#define NBORD 22847   // 384*384 - 353*353

__device__ inline float b2f(bf16 v){ return __bfloat162float(v); }
__device__ inline bf16  f2b(float v){ return __float2bfloat16(v); }
__device__ inline float sigm(float x){ return 1.f/(1.f+__expf(-x)); }

__device__ inline uint ab2(uint h, uint l){ return __builtin_amdgcn_alignbyte(h, l, 2); }

__device__ inline short8_t mk8p(uint2v a, uint2v b){
    union { uint u[4]; short8_t s; } t;
    t.u[0]=a[0]; t.u[1]=a[1]; t.u[2]=b[0]; t.u[3]=b[1]; return t.s;
}

// ---------------- K1: ci = sigmoid(pad1(conv3x3(inputs)+ic_b)), border = 0.5 ----------------
__global__ __launch_bounds__(256) void ci_kernel(const float* __restrict__ in,
                                                 const float* __restrict__ icw,
                                                 const float* __restrict__ icb,
                                                 bf16* __restrict__ ci)
{
    __shared__ float sw[108];
    __shared__ float sb[4];
    int tid = threadIdx.x;
    if (tid < 108) sw[tid] = icw[tid];
    if (tid < 4)   sb[tid] = icb[tid];
    __syncthreads();
    size_t idx = (size_t)blockIdx.x * 256 + tid;
    int x = (int)(idx % HH);
    int y = (int)((idx / HH) % HH);
    int b = (int)(idx / ((size_t)HH * HH));
    float v[4];
    if (y > 0 && y < HH-1 && x > 0 && x < HH-1) {
        float a0 = sb[0], a1 = sb[1], a2 = sb[2], a3 = sb[3];
        for (int ic = 0; ic < 3; ic++) {
            #pragma unroll
            for (int dy = 0; dy < 3; dy++) {
                #pragma unroll
                for (int dx = 0; dx < 3; dx++) {
                    float iv = in[((size_t)(b*3+ic)*HH + (y-1+dy))*HH + (x-1+dx)];
                    a0 = fmaf(iv, sw[0*27 + ic*9 + dy*3 + dx], a0);
                    a1 = fmaf(iv, sw[1*27 + ic*9 + dy*3 + dx], a1);
                    a2 = fmaf(iv, sw[2*27 + ic*9 + dy*3 + dx], a2);
                    a3 = fmaf(iv, sw[3*27 + ic*9 + dy*3 + dx], a3);
                }
            }
        }
        v[0]=sigm(a0); v[1]=sigm(a1); v[2]=sigm(a2); v[3]=sigm(a3);
    } else {
        v[0]=v[1]=v[2]=v[3]=0.5f;
    }
    #pragma unroll
    for (int o = 0; o < 4; o++)
        ci[((size_t)(b*4+o)*HH + y)*HH + x] = f2b(v[o]);
}

// ---- K2a-part: partial conv_feats over half the channels, full-GPU grid (256 blocks) ----
// part[((b*2+half)*16 + k)*1024 + hw] = sum_{cl=0..127} fm[b][half*128+cl][hw] * mcw[k][half*128+cl]
__global__ __launch_bounds__(256) void convfeats_part_kernel(const float* __restrict__ fm,
                                                             const float* __restrict__ mcw,
                                                             float* __restrict__ part)
{
    __shared__ float sw[128*16];   // [cl][k]
    int tid = threadIdx.x;
    int bx = blockIdx.x;
    int b = bx >> 3;
    int rem = bx & 7;
    int chunk = rem >> 1, half = rem & 1;
    for (int i = tid; i < 2048; i += 256) {
        int k = i >> 7, cl = i & 127;
        sw[cl*16 + k] = mcw[k*256 + half*128 + cl];
    }
    __syncthreads();
    int hw = chunk*256 + tid;
    float acc[16];
    #pragma unroll
    for (int k = 0; k < 16; k++) acc[k] = 0.f;
    const float* f = fm + (size_t)b*256*1024 + (size_t)(half*128)*1024 + hw;
    for (int cl = 0; cl < 128; cl++) {
        float v = f[(size_t)cl*1024];
        const float4* wp = (const float4*)(sw + cl*16);
        #pragma unroll
        for (int q = 0; q < 4; q++) {
            float4 t = wp[q];
            acc[q*4+0] = fmaf(v, t.x, acc[q*4+0]);
            acc[q*4+1] = fmaf(v, t.y, acc[q*4+1]);
            acc[q*4+2] = fmaf(v, t.z, acc[q*4+2]);
            acc[q*4+3] = fmaf(v, t.w, acc[q*4+3]);
        }
    }
    #pragma unroll
    for (int k = 0; k < 16; k++)
        part[(size_t)(b*2 + half)*16384 + k*1024 + hw] = acc[k];
}

// -------- K2c: wts = sigmoid((p0+p1+mcb)@(meta@mlW.T+mlb)) -> bf16 [b][16][1024] --------
__global__ __launch_bounds__(256) void wts_kernel(const float* __restrict__ meta,
                                                  const float* __restrict__ mlw,
                                                  const float* __restrict__ mlb,
                                                  const float* __restrict__ part,
                                                  const float* __restrict__ mcb,
                                                  bf16* __restrict__ wout)
{
    __shared__ float sm[64];
    __shared__ float sA[1024];
    __shared__ float sB[1024];
    int tid = threadIdx.x;
    int b = blockIdx.x >> 4, k = blockIdx.x & 15;
    if (tid < 64) sm[tid] = meta[(size_t)b*16*64 + k*64 + tid];
    float bk = mcb[k];
    #pragma unroll
    for (int q = 0; q < 4; q++) {
        int hw = q*256 + tid;
        sA[hw] = part[(size_t)(b*2 + 0)*16384 + k*1024 + hw]
               + part[(size_t)(b*2 + 1)*16384 + k*1024 + hw] + bk;
    }
    __syncthreads();
    #pragma unroll
    for (int q = 0; q < 4; q++) {
        int hw = q*256 + tid;
        const float4* wr = (const float4*)(mlw + (size_t)hw*64);
        float a = mlb[hw];
        #pragma unroll
        for (int d4 = 0; d4 < 16; d4++) {
            float4 t = wr[d4];
            a = fmaf(t.x, sm[d4*4+0], a);
            a = fmaf(t.y, sm[d4*4+1], a);
            a = fmaf(t.z, sm[d4*4+2], a);
            a = fmaf(t.w, sm[d4*4+3], a);
        }
        sB[hw] = a;
    }
    __syncthreads();
    #pragma unroll
    for (int q = 0; q < 4; q++) {
        int il = q*256 + tid;
        int i = il >> 5, l = il & 31;
        float a = 0.f;
        #pragma unroll
        for (int j = 0; j < 32; j++)
            a = fmaf(sA[i*32 + j], sB[j*32 + l], a);
        wout[(size_t)b*16384 + k*1024 + il] = f2b(sigm(a));
    }
}

// -------- A-fragment tables in MFMA lane order: [b][c][kyp][half][lane][8] --------
__global__ __launch_bounds__(256) void atab1F_kernel(const ushort* __restrict__ wts,
                                                     ushort* __restrict__ out)
{
    int g = blockIdx.x*256 + threadIdx.x;      // 32*4*39*2*64 = 638,976
    int lane = g & 63, half = (g >> 6) & 1;
    int rest = g >> 7;
    int kyp = rest % 39; int rest2 = rest / 39;
    int c = rest2 & 3, b = rest2 >> 2;
    int r = lane & 31, hi = lane >> 5;
    int dyA = r >> 2, mA = r & 3;
    int ch = mA*4 + c, ky = kyp - dyA, kx = 16*half + 8*hi;
    ushort v[8];
    if (ky >= 0 && ky < 32) {
        const ushort* src = wts + ((size_t)b*16 + ch)*1024 + ky*32 + kx;
        #pragma unroll
        for (int i=0;i<8;i++) v[i] = src[i];
    } else {
        #pragma unroll
        for (int i=0;i<8;i++) v[i] = 0;
    }
    __builtin_memcpy(out + (size_t)g*8, v, 16);
}

__global__ __launch_bounds__(256) void atab2F_kernel(const float* __restrict__ bbw,
                                                     ushort* __restrict__ out)
{
    int g = blockIdx.x*256 + threadIdx.x;      // 4*39*2*64 = 19,968
    int lane = g & 63, half = (g >> 6) & 1;
    int rest = g >> 7;
    int kyp = rest % 39;
    int c = rest / 39;
    int r = lane & 31, hi = lane >> 5;
    int dyA = r >> 2, mA = r & 3;
    int ch = mA*4 + c, ky = kyp - dyA, kx = 16*half + 8*hi;
    ushort v[8];
    if (ky >= 0 && ky < 32) {
        const float* src = bbw + (size_t)ch*1024 + ky*32 + kx;
        #pragma unroll
        for (int i=0;i<8;i++) { bf16 t = f2b(src[i]); v[i] = *(ushort*)&t; }
    } else {
        #pragma unroll
        for (int i=0;i<8;i++) v[i] = 0;
    }
    __builtin_memcpy(out + (size_t)g*8, v, 16);
}

// -------- border-zero kernels: zero the (15,16)-pad borders of [128][384][384] --------
// border px per image = 384^2 - 353^2 = 22,847: 31 full rows (0..14, 368..383) + 31 cols
// (0..14, 368..383) over the middle 353 rows.
__global__ __launch_bounds__(256) void bz16_kernel(ushort* __restrict__ out)
{
    int g = blockIdx.x*256 + threadIdx.x;
    if (g >= NBORD*128) return;
    int i = g % NBORD, bc = g / NBORD;
    int y, x;
    if (i < 11904) { int r = i / 384; y = (r < 15) ? r : 353 + r; x = i % 384; }
    else { int j = i - 11904; y = 15 + j / 31; int cc = j % 31; x = (cc < 15) ? cc : 353 + cc; }
    out[(size_t)bc*HW + (size_t)y*HH + x] = 0;
}

__global__ __launch_bounds__(256) void bz32_kernel(float* __restrict__ out)
{
    int g = blockIdx.x*256 + threadIdx.x;
    if (g >= NBORD*128) return;
    int i = g % NBORD, bc = g / NBORD;
    int y, x;
    if (i < 11904) { int r = i / 384; y = (r < 15) ? r : 353 + r; x = i % 384; }
    else { int j = i - 11904; y = 15 + j / 31; int cc = j % 31; x = (cc < 15) ? cc : 353 + cc; }
    out[(size_t)bc*HW + (size_t)y*HH + x] = 0.f;
}

// ================= duo-tile conv (r15, proven): 64-col waves, 3 waves/SIMD =================
// Wave: 16 out rows x 64 cols (T1 rows +0..7, T2 +8..15; 2 col strips). Block = 4 waves
// = 2 row-groups (0/16) x 2 x-strips (0/64) -> 32 rows x 128 cols. 47 steps/channel.
// LDS: 63 rows x 160 words (copy0 80 | copy1 80, bank-shift 16) = 40,320 B -> 3 blocks/CU.
// NO setprio (r14/r15 A/B: corrupts).
#define G_LOADX4(dst, addr, OFF) \
    asm volatile("global_load_dwordx4 %0, %1, off offset:" OFF : "=v"(dst) : "v"(addr))

#define ISSUE_A(A0_, A1_, ap_, e_)                                   \
{                                                                    \
    const ushort* p_ = (ap_) + (unsigned)(e_)*1024u;                 \
    G_LOADX4(A0_, p_, "0");                                          \
    G_LOADX4(A1_, p_, "1024");                                       \
}

#define ISSUE_B8(S, ADDR)                                                    \
    asm volatile(                                                            \
        "ds_read2_b32 %0, %8 offset0:0 offset1:1\n\t"                        \
        "ds_read2_b32 %1, %8 offset0:2 offset1:3\n\t"                        \
        "ds_read2_b32 %2, %8 offset0:8 offset1:9\n\t"                        \
        "ds_read2_b32 %3, %8 offset0:10 offset1:11\n\t"                      \
        "ds_read2_b32 %4, %8 offset0:16 offset1:17\n\t"                      \
        "ds_read2_b32 %5, %8 offset0:18 offset1:19\n\t"                      \
        "ds_read2_b32 %6, %8 offset0:24 offset1:25\n\t"                      \
        "ds_read2_b32 %7, %8 offset0:26 offset1:27"                          \
        : "=v"(S[0]), "=v"(S[1]), "=v"(S[2]), "=v"(S[3]), "=v"(S[4]),        \
          "=v"(S[5]), "=v"(S[6]), "=v"(S[7])                                 \
        : "v"(ADDR) : "memory")

#define KWAIT(VN, LN) do {                                                      \
    asm volatile("s_waitcnt vmcnt(" VN ") lgkmcnt(" LN ")" ::: "memory");       \
    __builtin_amdgcn_sched_barrier(0); } while (0)

#define MMp(acc_, A_, Pa, Pb) \
    acc_ = __builtin_amdgcn_mfma_f32_32x32x16_bf16(A_, mk8p(Pa, Pb), acc_, 0, 0, 0)

// T1-only: 4 MFMA (2 strips x 2 K-halves), same-acc distance 2
#define STEP1B(S, A0_, A1_, VN, LN) { KWAIT(VN, LN);                          \
    MMp(q0, A0_, S[0], S[1]);  MMp(q1, A0_, S[4], S[5]);                      \
    MMp(q0, A1_, S[2], S[3]);  MMp(q1, A1_, S[6], S[7]); }

#define STEP2B(S, C0_, C1_, VN, LN) { KWAIT(VN, LN);                          \
    MMp(u0, C0_, S[0], S[1]);  MMp(u1, C0_, S[4], S[5]);                      \
    MMp(u0, C1_, S[2], S[3]);  MMp(u1, C1_, S[6], S[7]); }

// both tiles: 8 MFMA, same-acc distance 4; q/u pairs share a B quad
#define STEP12B(S, A0_, A1_, C0_, C1_, VN, LN) { KWAIT(VN, LN);               \
    MMp(q0, A0_, S[0], S[1]);   MMp(u0, C0_, S[0], S[1]);                     \
    MMp(q1, A0_, S[4], S[5]);   MMp(u1, C0_, S[4], S[5]);                     \
    MMp(q0, A1_, S[2], S[3]);   MMp(u0, C1_, S[2], S[3]);                     \
    MMp(q1, A1_, S[6], S[7]);   MMp(u1, C1_, S[6], S[7]); }

template<bool PER_B, bool OUT_BF16, bool ADD_BIAS>
__global__ __launch_bounds__(256, 3) void conv32_duo(const ushort* __restrict__ in,
                                                     const ushort* __restrict__ atabF,
                                                     const float* __restrict__ bias,
                                                     void* __restrict__ outp)
{
    __shared__ uint sbuf[63*160];   // 40,320 B

    // XCD-chunk swizzle (1152 % 8 == 0)
    int d = blockIdx.x;
    int L = (d & 7) * 144 + (d >> 3);
    int b = L / 36; int rem = L % 36;
    int yb = rem / 3, xb = rem % 3;
    int yv = yb * 32;
    int x0 = xb * 128;

    int tid = threadIdx.x;
    int l = tid & 63, w = tid >> 6;
    int rg = (w >> 1) * 16;            // row-group 0 / 16
    int xs = (w & 1) * 64;             // local x start within 128-col block
    int hi = l >> 5;

    int s = xs + (l & 31) + 8*hi;      // local start element (0..103)
    int p = s & 1;
    const uint* swl = sbuf + (unsigned)(rg*160) + (unsigned)(p*80 + ((s - p) >> 1));
    uint baddr0 = (uint)(size_t)(const void*)swl;   // LDS byte offset

    f32x16 q0, q1, u0, u1;
    #pragma unroll
    for (int i = 0; i < 16; i++) { q0[i]=0.f; q1[i]=0.f; u0[i]=0.f; u1[i]=0.f; }

    unsigned chbase0 = (unsigned)b*589824u + (unsigned)yv*384u + (unsigned)x0;

    for (int c = 0; c < 4; ++c) {
        if (c) __syncthreads();
        // ---- stage channel c: local rows 0..62 (image rows yv..yv+62), 160 el + parity copy ----
        unsigned chb = chbase0 + (unsigned)c*147456u;
        for (int qq = tid; qq < 1260; qq += 256) {     // 63 rows * 20 chunks of 8 el
            int row = qq / 20, k = qq - row*20;
            unsigned gi = chb + (unsigned)row*384u + (unsigned)k*8u;
            if (gi > TOT_ELEMS - 16u) gi = TOT_ELEMS - 16u;
            const uint* gp = (const uint*)(in + gi);   // 16B aligned
            uint d0 = gp[0], d1 = gp[1], d2 = gp[2], d3 = gp[3], d4 = gp[4];
            unsigned widx = (unsigned)row*160u + (unsigned)k*4u;
            uint4* w0 = (uint4*)&sbuf[widx];
            uint4* w1 = (uint4*)&sbuf[widx + 80u];
            *w0 = make_uint4(d0, d1, d2, d3);
            *w1 = make_uint4(ab2(d1,d0), ab2(d2,d1), ab2(d3,d2), ab2(d4,d3));
        }
        __syncthreads();

        const ushort* ap1 = atabF + (size_t)((PER_B ? (b*4 + c) : c) * 39) * 1024 + l*8;
        short8_t xA0, xA1, x20, x21;      // A sets
        short8_t yA0, yA1, y20, y21;
        uint2v sE[8], sO[8];              // B double buffer
        uint baddr = baddr0;

        ISSUE_B8(sE, baddr); baddr += 640u;
        ISSUE_A(xA0, xA1, ap1, 0);

        // ---- P1: steps 0..7, T1 only ----
        ISSUE_B8(sO, baddr); baddr += 640u;
        ISSUE_A(yA0, yA1, ap1, 1);
        STEP1B(sE, xA0, xA1, "2", "8");
        ISSUE_B8(sE, baddr); baddr += 640u;
        ISSUE_A(xA0, xA1, ap1, 2);
        STEP1B(sO, yA0, yA1, "2", "8");
        ISSUE_B8(sO, baddr); baddr += 640u;
        ISSUE_A(yA0, yA1, ap1, 3);
        STEP1B(sE, xA0, xA1, "2", "8");
        ISSUE_B8(sE, baddr); baddr += 640u;
        ISSUE_A(xA0, xA1, ap1, 4);
        STEP1B(sO, yA0, yA1, "2", "8");
        ISSUE_B8(sO, baddr); baddr += 640u;
        ISSUE_A(yA0, yA1, ap1, 5);
        STEP1B(sE, xA0, xA1, "2", "8");
        ISSUE_B8(sE, baddr); baddr += 640u;
        ISSUE_A(xA0, xA1, ap1, 6);
        STEP1B(sO, yA0, yA1, "2", "8");
        ISSUE_B8(sO, baddr); baddr += 640u;
        ISSUE_A(yA0, yA1, ap1, 7);
        STEP1B(sE, xA0, xA1, "2", "8");
        ISSUE_B8(sE, baddr); baddr += 640u;
        ISSUE_A(xA0, xA1, ap1, 8);
        ISSUE_A(x20, x21, ap1, 0);
        STEP1B(sO, yA0, yA1, "4", "8");

        // ---- P2: steps 8..37, both tiles (T1 entry r, T2 entry r-8) ----
        #pragma unroll 1
        for (int t = 0; t < 15; ++t) {
            int r = 8 + 2*t;
            ISSUE_B8(sO, baddr); baddr += 640u;
            ISSUE_A(yA0, yA1, ap1, r+1); ISSUE_A(y20, y21, ap1, r-7);
            STEP12B(sE, xA0, xA1, x20, x21, "4", "8");
            ISSUE_B8(sE, baddr); baddr += 640u;
            ISSUE_A(xA0, xA1, ap1, r+2); ISSUE_A(x20, x21, ap1, r-6);
            STEP12B(sO, yA0, yA1, y20, y21, "4", "8");
        }
        // ---- step 38 ----
        ISSUE_B8(sO, baddr); baddr += 640u;
        ISSUE_A(y20, y21, ap1, 31);
        STEP12B(sE, xA0, xA1, x20, x21, "2", "8");

        // ---- P3: steps 39..46, T2 only (entries 31..38) ----
        ISSUE_B8(sE, baddr); baddr += 640u; ISSUE_A(x20, x21, ap1, 32); STEP2B(sO, y20, y21, "2", "8");
        ISSUE_B8(sO, baddr); baddr += 640u; ISSUE_A(y20, y21, ap1, 33); STEP2B(sE, x20, x21, "2", "8");
        ISSUE_B8(sE, baddr); baddr += 640u; ISSUE_A(x20, x21, ap1, 34); STEP2B(sO, y20, y21, "2", "8");
        ISSUE_B8(sO, baddr); baddr += 640u; ISSUE_A(y20, y21, ap1, 35); STEP2B(sE, x20, x21, "2", "8");
        ISSUE_B8(sE, baddr); baddr += 640u; ISSUE_A(x20, x21, ap1, 36); STEP2B(sO, y20, y21, "2", "8");
        ISSUE_B8(sO, baddr); baddr += 640u; ISSUE_A(y20, y21, ap1, 37); STEP2B(sE, x20, x21, "2", "8");
        ISSUE_B8(sE, baddr); baddr += 640u; ISSUE_A(x20, x21, ap1, 38); STEP2B(sO, y20, y21, "2", "8");
        STEP2B(sE, x20, x21, "0", "0");

        asm volatile("s_waitcnt vmcnt(0) lgkmcnt(0)" ::: "memory");
    }

    float bv0 = 0.f, bv1 = 0.f, bv2 = 0.f, bv3 = 0.f;
    if (ADD_BIAS) { bv0 = bias[0]; bv1 = bias[1]; bv2 = bias[2]; bv3 = bias[3]; }

    #pragma unroll
    for (int j = 0; j < 2; j++) {
        int ox = x0 + xs + 32*j + (l & 31);
        if (ox > 352) continue;
        int px = ox + 15;
        #pragma unroll
        for (int rgi = 0; rgi < 16; rgi++) {
            int m  = rgi & 3;
            int dy = 2*(rgi >> 2) + hi;
            float v1 = (j == 0 ? q0[rgi] : q1[rgi]);
            float v2 = (j == 0 ? u0[rgi] : u1[rgi]);
            float bb = (m == 0 ? bv0 : m == 1 ? bv1 : m == 2 ? bv2 : bv3);
            int oy1 = yv + rg + dy;
            if (oy1 <= 352) {
                size_t o = ((size_t)(b*4 + m))*HW + (size_t)(oy1 + 15)*HH + px;
                float v = v1 + (ADD_BIAS ? bb : 0.f);
                if constexpr (OUT_BF16) ((bf16*)outp)[o] = f2b(v);
                else                    ((float*)outp)[o] = v;
            }
            int oy2 = yv + rg + 8 + dy;
            if (oy2 <= 352) {
                size_t o = ((size_t)(b*4 + m))*HW + (size_t)(oy2 + 15)*HH + px;
                float v = v2 + (ADD_BIAS ? bb : 0.f);
                if constexpr (OUT_BF16) ((bf16*)outp)[o] = f2b(v);
                else                    ((float*)outp)[o] = v;
            }
        }
    }
}

extern "C" void kernel_launch(void* const* d_in, const int* in_sizes, int n_in,
                              void* d_out, int out_size, void* d_ws, size_t ws_size,
                              hipStream_t stream)
{
    const float* inputs = (const float*)d_in[0];
    const float* fm     = (const float*)d_in[1];
    const float* meta   = (const float*)d_in[2];
    const float* mcw    = (const float*)d_in[3];
    const float* mcb    = (const float*)d_in[4];
    const float* mlw    = (const float*)d_in[5];
    const float* mlb    = (const float*)d_in[6];
    const float* icw    = (const float*)d_in[7];
    const float* icb    = (const float*)d_in[8];
    const float* bbw    = (const float*)d_in[9];
    const float* bbb    = (const float*)d_in[10];

    // workspace layout (bytes):
    //   ci     bf16 [32,4,384,384]      @ 0           37,748,736
    //   mapped bf16 [32,4,384,384]      @ 37,748,736  37,748,736
    //     (first 4 MB of mapped doubles as f32 partials [32][2][16][1024] before conv1)
    //   wts    bf16 [32,16,1024]        @ 77,594,624   1,048,576   (cf slot reused)
    //   atab1F bf16 [32,4,39,2,64,8]    @ 78,643,200  10,223,616
    //   atab2F bf16 [4,39,2,64,8]       @ 88,866,816     319,488
    char* ws = (char*)d_ws;
    bf16*   ci     = (bf16*) ws;
    bf16*   mapped = (bf16*)(ws + 37748736);
    float*  part   = (float*)(ws + 37748736);      // partials overlay (read before conv1)
    bf16*   wts    = (bf16*)(ws + 77594624);
    ushort* atab1F = (ushort*)(ws + 78643200);
    ushort* atab2F = (ushort*)(ws + 88866816);

    ci_kernel<<<18432, 256, 0, stream>>>(inputs, icw, icb, ci);
    convfeats_part_kernel<<<256, 256, 0, stream>>>(fm, mcw, part);
    wts_kernel<<<512, 256, 0, stream>>>(meta, mlw, mlb, part, mcb, wts);
    atab1F_kernel<<<2496, 256, 0, stream>>>((const ushort*)wts, atab1F);
    atab2F_kernel<<<78, 256, 0, stream>>>(bbw, atab2F);

    // border zeros (replaces full-buffer memsets; interiors fully rewritten by convs)
    bz16_kernel<<<11424, 256, 0, stream>>>((ushort*)mapped);
    conv32_duo<true, true, false><<<1152, 256, 0, stream>>>(
        (const ushort*)ci, atab1F, nullptr, mapped);

    bz32_kernel<<<11424, 256, 0, stream>>>((float*)d_out);
    conv32_duo<false, false, true><<<1152, 256, 0, stream>>>(
        (const ushort*)mapped, atab2F, bbb, d_out);
}

// Round 20
// 410.904 us; speedup vs baseline: 1.1489x; 1.0042x over previous
//
#include <hip/hip_runtime.h>
#include <hip/hip_bf16.h>

typedef __hip_bfloat16 bf16;
typedef __attribute__((ext_vector_type(8))) short short8_t;
typedef __attribute__((ext_vector_type(16))) float f32x16;
typedef __attribute__((ext_vector_type(2))) unsigned int uint2v;

#define HH 384
#define HW (384*384)
#define TOT_ELEMS (32u*4u*147456u)
#define NBORD 22847   // 384*384 - 353*353

// fused_pre block ranges
#define CI_END   18432
#define CF_END   (CI_END + 256)
#define AT2_END  (CF_END + 78)
#define BZ16_END (AT2_END + 11424)
#define FUSED_GRID (BZ16_END + 11424)

__device__ inline float b2f(bf16 v){ return __bfloat162float(v); }
__device__ inline bf16  f2b(float v){ return __float2bfloat16(v); }
__device__ inline float sigm(float x){ return 1.f/(1.f+__expf(-x)); }

__device__ inline uint ab2(uint h, uint l){ return __builtin_amdgcn_alignbyte(h, l, 2); }

__device__ inline short8_t mk8p(uint2v a, uint2v b){
    union { uint u[4]; short8_t s; } t;
    t.u[0]=a[0]; t.u[1]=a[1]; t.u[2]=b[0]; t.u[3]=b[1]; return t.s;
}

// ================= fused prologue: ci | convfeats_part | atab2F | bz16 | bz32 =================
__global__ __launch_bounds__(256) void fused_pre(const float* __restrict__ in,
                                                 const float* __restrict__ icw,
                                                 const float* __restrict__ icb,
                                                 bf16* __restrict__ ci,
                                                 const float* __restrict__ fm,
                                                 const float* __restrict__ mcw,
                                                 float* __restrict__ part,
                                                 const float* __restrict__ bbw,
                                                 ushort* __restrict__ atab2F,
                                                 ushort* __restrict__ mapped_bz,
                                                 float* __restrict__ out_bz)
{
    __shared__ float fsm[2048];
    int tid = threadIdx.x;
    int bx = blockIdx.x;

    if (bx < CI_END) {
        // ---- ci: sigmoid(pad1(conv3x3(inputs)+ic_b)), border = 0.5 ----
        float* sw = fsm;          // 108
        float* sb = fsm + 108;    // 4
        if (tid < 108) sw[tid] = icw[tid];
        if (tid < 4)   sb[tid] = icb[tid];
        __syncthreads();
        size_t idx = (size_t)bx * 256 + tid;
        int x = (int)(idx % HH);
        int y = (int)((idx / HH) % HH);
        int b = (int)(idx / ((size_t)HH * HH));
        float v[4];
        if (y > 0 && y < HH-1 && x > 0 && x < HH-1) {
            float a0 = sb[0], a1 = sb[1], a2 = sb[2], a3 = sb[3];
            for (int ic = 0; ic < 3; ic++) {
                #pragma unroll
                for (int dy = 0; dy < 3; dy++) {
                    #pragma unroll
                    for (int dx = 0; dx < 3; dx++) {
                        float iv = in[((size_t)(b*3+ic)*HH + (y-1+dy))*HH + (x-1+dx)];
                        a0 = fmaf(iv, sw[0*27 + ic*9 + dy*3 + dx], a0);
                        a1 = fmaf(iv, sw[1*27 + ic*9 + dy*3 + dx], a1);
                        a2 = fmaf(iv, sw[2*27 + ic*9 + dy*3 + dx], a2);
                        a3 = fmaf(iv, sw[3*27 + ic*9 + dy*3 + dx], a3);
                    }
                }
            }
            v[0]=sigm(a0); v[1]=sigm(a1); v[2]=sigm(a2); v[3]=sigm(a3);
        } else {
            v[0]=v[1]=v[2]=v[3]=0.5f;
        }
        #pragma unroll
        for (int o = 0; o < 4; o++)
            ci[((size_t)(b*4+o)*HH + y)*HH + x] = f2b(v[o]);
        return;
    }
    if (bx < CF_END) {
        // ---- convfeats partial: half the channels, 256 blocks ----
        int bb = bx - CI_END;
        int b = bb >> 3;
        int rem = bb & 7;
        int chunk = rem >> 1, half = rem & 1;
        float* sw = fsm;   // [cl][k], 2048
        for (int i = tid; i < 2048; i += 256) {
            int k = i >> 7, cl = i & 127;
            sw[cl*16 + k] = mcw[k*256 + half*128 + cl];
        }
        __syncthreads();
        int hw = chunk*256 + tid;
        float acc[16];
        #pragma unroll
        for (int k = 0; k < 16; k++) acc[k] = 0.f;
        const float* f = fm + (size_t)b*256*1024 + (size_t)(half*128)*1024 + hw;
        for (int cl = 0; cl < 128; cl++) {
            float v = f[(size_t)cl*1024];
            const float4* wp = (const float4*)(sw + cl*16);
            #pragma unroll
            for (int q = 0; q < 4; q++) {
                float4 t = wp[q];
                acc[q*4+0] = fmaf(v, t.x, acc[q*4+0]);
                acc[q*4+1] = fmaf(v, t.y, acc[q*4+1]);
                acc[q*4+2] = fmaf(v, t.z, acc[q*4+2]);
                acc[q*4+3] = fmaf(v, t.w, acc[q*4+3]);
            }
        }
        #pragma unroll
        for (int k = 0; k < 16; k++)
            part[(size_t)(b*2 + half)*16384 + k*1024 + hw] = acc[k];
        return;
    }
    if (bx < AT2_END) {
        // ---- atab2F: bbw -> MFMA lane order ----
        int g = (bx - CF_END)*256 + tid;
        if (g >= 4*39*2*64) return;
        int lane = g & 63, half = (g >> 6) & 1;
        int rest = g >> 7;
        int kyp = rest % 39;
        int c = rest / 39;
        int r = lane & 31, hi = lane >> 5;
        int dyA = r >> 2, mA = r & 3;
        int ch = mA*4 + c, ky = kyp - dyA, kx = 16*half + 8*hi;
        ushort v[8];
        if (ky >= 0 && ky < 32) {
            const float* src = bbw + (size_t)ch*1024 + ky*32 + kx;
            #pragma unroll
            for (int i=0;i<8;i++) { bf16 t = f2b(src[i]); v[i] = *(ushort*)&t; }
        } else {
            #pragma unroll
            for (int i=0;i<8;i++) v[i] = 0;
        }
        __builtin_memcpy(atab2F + (size_t)g*8, v, 16);
        return;
    }
    if (bx < BZ16_END) {
        // ---- bz16: zero borders of mapped ----
        int g = (bx - AT2_END)*256 + tid;
        if (g >= NBORD*128) return;
        int i = g % NBORD, bc = g / NBORD;
        int y, x;
        if (i < 11904) { int r = i / 384; y = (r < 15) ? r : 353 + r; x = i % 384; }
        else { int j = i - 11904; y = 15 + j / 31; int cc = j % 31; x = (cc < 15) ? cc : 353 + cc; }
        mapped_bz[(size_t)bc*HW + (size_t)y*HH + x] = 0;
        return;
    }
    {
        // ---- bz32: zero borders of d_out ----
        int g = (bx - BZ16_END)*256 + tid;
        if (g >= NBORD*128) return;
        int i = g % NBORD, bc = g / NBORD;
        int y, x;
        if (i < 11904) { int r = i / 384; y = (r < 15) ? r : 353 + r; x = i % 384; }
        else { int j = i - 11904; y = 15 + j / 31; int cc = j % 31; x = (cc < 15) ? cc : 353 + cc; }
        out_bz[(size_t)bc*HW + (size_t)y*HH + x] = 0.f;
    }
}

// -------- K2c: wts = sigmoid((p0+p1+mcb)@(meta@mlW.T+mlb)) -> bf16 [b][16][1024] --------
__global__ __launch_bounds__(256) void wts_kernel(const float* __restrict__ meta,
                                                  const float* __restrict__ mlw,
                                                  const float* __restrict__ mlb,
                                                  const float* __restrict__ part,
                                                  const float* __restrict__ mcb,
                                                  bf16* __restrict__ wout)
{
    __shared__ float sm[64];
    __shared__ float sA[1024];
    __shared__ float sB[1024];
    int tid = threadIdx.x;
    int b = blockIdx.x >> 4, k = blockIdx.x & 15;
    if (tid < 64) sm[tid] = meta[(size_t)b*16*64 + k*64 + tid];
    float bk = mcb[k];
    #pragma unroll
    for (int q = 0; q < 4; q++) {
        int hw = q*256 + tid;
        sA[hw] = part[(size_t)(b*2 + 0)*16384 + k*1024 + hw]
               + part[(size_t)(b*2 + 1)*16384 + k*1024 + hw] + bk;
    }
    __syncthreads();
    #pragma unroll
    for (int q = 0; q < 4; q++) {
        int hw = q*256 + tid;
        const float4* wr = (const float4*)(mlw + (size_t)hw*64);
        float a = mlb[hw];
        #pragma unroll
        for (int d4 = 0; d4 < 16; d4++) {
            float4 t = wr[d4];
            a = fmaf(t.x, sm[d4*4+0], a);
            a = fmaf(t.y, sm[d4*4+1], a);
            a = fmaf(t.z, sm[d4*4+2], a);
            a = fmaf(t.w, sm[d4*4+3], a);
        }
        sB[hw] = a;
    }
    __syncthreads();
    #pragma unroll
    for (int q = 0; q < 4; q++) {
        int il = q*256 + tid;
        int i = il >> 5, l = il & 31;
        float a = 0.f;
        #pragma unroll
        for (int j = 0; j < 32; j++)
            a = fmaf(sA[i*32 + j], sB[j*32 + l], a);
        wout[(size_t)b*16384 + k*1024 + il] = f2b(sigm(a));
    }
}

// -------- atab1F: wts -> MFMA lane order [b][c][kyp][half][lane][8] --------
__global__ __launch_bounds__(256) void atab1F_kernel(const ushort* __restrict__ wts,
                                                     ushort* __restrict__ out)
{
    int g = blockIdx.x*256 + threadIdx.x;      // 32*4*39*2*64 = 638,976
    int lane = g & 63, half = (g >> 6) & 1;
    int rest = g >> 7;
    int kyp = rest % 39; int rest2 = rest / 39;
    int c = rest2 & 3, b = rest2 >> 2;
    int r = lane & 31, hi = lane >> 5;
    int dyA = r >> 2, mA = r & 3;
    int ch = mA*4 + c, ky = kyp - dyA, kx = 16*half + 8*hi;
    ushort v[8];
    if (ky >= 0 && ky < 32) {
        const ushort* src = wts + ((size_t)b*16 + ch)*1024 + ky*32 + kx;
        #pragma unroll
        for (int i=0;i<8;i++) v[i] = src[i];
    } else {
        #pragma unroll
        for (int i=0;i<8;i++) v[i] = 0;
    }
    __builtin_memcpy(out + (size_t)g*8, v, 16);
}

// ================= duo-tile conv (r15, proven): 64-col waves, 3 waves/SIMD =================
// Wave: 16 out rows x 64 cols (T1 rows +0..7, T2 +8..15; 2 col strips). Block = 4 waves
// = 2 row-groups (0/16) x 2 x-strips (0/64) -> 32 rows x 128 cols. 47 steps/channel.
// LDS: 63 rows x 160 words (copy0 80 | copy1 80, bank-shift 16) = 40,320 B -> 3 blocks/CU.
// NO setprio (r14/r15 A/B: corrupts).
#define G_LOADX4(dst, addr, OFF) \
    asm volatile("global_load_dwordx4 %0, %1, off offset:" OFF : "=v"(dst) : "v"(addr))

#define ISSUE_A(A0_, A1_, ap_, e_)                                   \
{                                                                    \
    const ushort* p_ = (ap_) + (unsigned)(e_)*1024u;                 \
    G_LOADX4(A0_, p_, "0");                                          \
    G_LOADX4(A1_, p_, "1024");                                       \
}

#define ISSUE_B8(S, ADDR)                                                    \
    asm volatile(                                                            \
        "ds_read2_b32 %0, %8 offset0:0 offset1:1\n\t"                        \
        "ds_read2_b32 %1, %8 offset0:2 offset1:3\n\t"                        \
        "ds_read2_b32 %2, %8 offset0:8 offset1:9\n\t"                        \
        "ds_read2_b32 %3, %8 offset0:10 offset1:11\n\t"                      \
        "ds_read2_b32 %4, %8 offset0:16 offset1:17\n\t"                      \
        "ds_read2_b32 %5, %8 offset0:18 offset1:19\n\t"                      \
        "ds_read2_b32 %6, %8 offset0:24 offset1:25\n\t"                      \
        "ds_read2_b32 %7, %8 offset0:26 offset1:27"                          \
        : "=v"(S[0]), "=v"(S[1]), "=v"(S[2]), "=v"(S[3]), "=v"(S[4]),        \
          "=v"(S[5]), "=v"(S[6]), "=v"(S[7])                                 \
        : "v"(ADDR) : "memory")

#define KWAIT(VN, LN) do {                                                      \
    asm volatile("s_waitcnt vmcnt(" VN ") lgkmcnt(" LN ")" ::: "memory");       \
    __builtin_amdgcn_sched_barrier(0); } while (0)

#define MMp(acc_, A_, Pa, Pb) \
    acc_ = __builtin_amdgcn_mfma_f32_32x32x16_bf16(A_, mk8p(Pa, Pb), acc_, 0, 0, 0)

// T1-only: 4 MFMA (2 strips x 2 K-halves), same-acc distance 2
#define STEP1B(S, A0_, A1_, VN, LN) { KWAIT(VN, LN);                          \
    MMp(q0, A0_, S[0], S[1]);  MMp(q1, A0_, S[4], S[5]);                      \
    MMp(q0, A1_, S[2], S[3]);  MMp(q1, A1_, S[6], S[7]); }

#define STEP2B(S, C0_, C1_, VN, LN) { KWAIT(VN, LN);                          \
    MMp(u0, C0_, S[0], S[1]);  MMp(u1, C0_, S[4], S[5]);                      \
    MMp(u0, C1_, S[2], S[3]);  MMp(u1, C1_, S[6], S[7]); }

// both tiles: 8 MFMA, same-acc distance 4; q/u pairs share a B quad
#define STEP12B(S, A0_, A1_, C0_, C1_, VN, LN) { KWAIT(VN, LN);               \
    MMp(q0, A0_, S[0], S[1]);   MMp(u0, C0_, S[0], S[1]);                     \
    MMp(q1, A0_, S[4], S[5]);   MMp(u1, C0_, S[4], S[5]);                     \
    MMp(q0, A1_, S[2], S[3]);   MMp(u0, C1_, S[2], S[3]);                     \
    MMp(q1, A1_, S[6], S[7]);   MMp(u1, C1_, S[6], S[7]); }

template<bool PER_B, bool OUT_BF16, bool ADD_BIAS>
__global__ __launch_bounds__(256, 3) void conv32_duo(const ushort* __restrict__ in,
                                                     const ushort* __restrict__ atabF,
                                                     const float* __restrict__ bias,
                                                     void* __restrict__ outp)
{
    __shared__ uint sbuf[63*160];   // 40,320 B

    // XCD-chunk swizzle (1152 % 8 == 0)
    int d = blockIdx.x;
    int L = (d & 7) * 144 + (d >> 3);
    int b = L / 36; int rem = L % 36;
    int yb = rem / 3, xb = rem % 3;
    int yv = yb * 32;
    int x0 = xb * 128;

    int tid = threadIdx.x;
    int l = tid & 63, w = tid >> 6;
    int rg = (w >> 1) * 16;            // row-group 0 / 16
    int xs = (w & 1) * 64;             // local x start within 128-col block
    int hi = l >> 5;

    int s = xs + (l & 31) + 8*hi;      // local start element (0..103)
    int p = s & 1;
    const uint* swl = sbuf + (unsigned)(rg*160) + (unsigned)(p*80 + ((s - p) >> 1));
    uint baddr0 = (uint)(size_t)(const void*)swl;   // LDS byte offset

    f32x16 q0, q1, u0, u1;
    #pragma unroll
    for (int i = 0; i < 16; i++) { q0[i]=0.f; q1[i]=0.f; u0[i]=0.f; u1[i]=0.f; }

    unsigned chbase0 = (unsigned)b*589824u + (unsigned)yv*384u + (unsigned)x0;

    for (int c = 0; c < 4; ++c) {
        if (c) __syncthreads();
        // ---- stage channel c: local rows 0..62 (image rows yv..yv+62), 160 el + parity copy ----
        unsigned chb = chbase0 + (unsigned)c*147456u;
        for (int qq = tid; qq < 1260; qq += 256) {     // 63 rows * 20 chunks of 8 el
            int row = qq / 20, k = qq - row*20;
            unsigned gi = chb + (unsigned)row*384u + (unsigned)k*8u;
            if (gi > TOT_ELEMS - 16u) gi = TOT_ELEMS - 16u;
            const uint* gp = (const uint*)(in + gi);   // 16B aligned
            uint d0 = gp[0], d1 = gp[1], d2 = gp[2], d3 = gp[3], d4 = gp[4];
            unsigned widx = (unsigned)row*160u + (unsigned)k*4u;
            uint4* w0 = (uint4*)&sbuf[widx];
            uint4* w1 = (uint4*)&sbuf[widx + 80u];
            *w0 = make_uint4(d0, d1, d2, d3);
            *w1 = make_uint4(ab2(d1,d0), ab2(d2,d1), ab2(d3,d2), ab2(d4,d3));
        }
        __syncthreads();

        const ushort* ap1 = atabF + (size_t)((PER_B ? (b*4 + c) : c) * 39) * 1024 + l*8;
        short8_t xA0, xA1, x20, x21;      // A sets
        short8_t yA0, yA1, y20, y21;
        uint2v sE[8], sO[8];              // B double buffer
        uint baddr = baddr0;

        ISSUE_B8(sE, baddr); baddr += 640u;
        ISSUE_A(xA0, xA1, ap1, 0);

        // ---- P1: steps 0..7, T1 only ----
        ISSUE_B8(sO, baddr); baddr += 640u;
        ISSUE_A(yA0, yA1, ap1, 1);
        STEP1B(sE, xA0, xA1, "2", "8");
        ISSUE_B8(sE, baddr); baddr += 640u;
        ISSUE_A(xA0, xA1, ap1, 2);
        STEP1B(sO, yA0, yA1, "2", "8");
        ISSUE_B8(sO, baddr); baddr += 640u;
        ISSUE_A(yA0, yA1, ap1, 3);
        STEP1B(sE, xA0, xA1, "2", "8");
        ISSUE_B8(sE, baddr); baddr += 640u;
        ISSUE_A(xA0, xA1, ap1, 4);
        STEP1B(sO, yA0, yA1, "2", "8");
        ISSUE_B8(sO, baddr); baddr += 640u;
        ISSUE_A(yA0, yA1, ap1, 5);
        STEP1B(sE, xA0, xA1, "2", "8");
        ISSUE_B8(sE, baddr); baddr += 640u;
        ISSUE_A(xA0, xA1, ap1, 6);
        STEP1B(sO, yA0, yA1, "2", "8");
        ISSUE_B8(sO, baddr); baddr += 640u;
        ISSUE_A(yA0, yA1, ap1, 7);
        STEP1B(sE, xA0, xA1, "2", "8");
        ISSUE_B8(sE, baddr); baddr += 640u;
        ISSUE_A(xA0, xA1, ap1, 8);
        ISSUE_A(x20, x21, ap1, 0);
        STEP1B(sO, yA0, yA1, "4", "8");

        // ---- P2: steps 8..37, both tiles (T1 entry r, T2 entry r-8) ----
        #pragma unroll 1
        for (int t = 0; t < 15; ++t) {
            int r = 8 + 2*t;
            ISSUE_B8(sO, baddr); baddr += 640u;
            ISSUE_A(yA0, yA1, ap1, r+1); ISSUE_A(y20, y21, ap1, r-7);
            STEP12B(sE, xA0, xA1, x20, x21, "4", "8");
            ISSUE_B8(sE, baddr); baddr += 640u;
            ISSUE_A(xA0, xA1, ap1, r+2); ISSUE_A(x20, x21, ap1, r-6);
            STEP12B(sO, yA0, yA1, y20, y21, "4", "8");
        }
        // ---- step 38 ----
        ISSUE_B8(sO, baddr); baddr += 640u;
        ISSUE_A(y20, y21, ap1, 31);
        STEP12B(sE, xA0, xA1, x20, x21, "2", "8");

        // ---- P3: steps 39..46, T2 only (entries 31..38) ----
        ISSUE_B8(sE, baddr); baddr += 640u; ISSUE_A(x20, x21, ap1, 32); STEP2B(sO, y20, y21, "2", "8");
        ISSUE_B8(sO, baddr); baddr += 640u; ISSUE_A(y20, y21, ap1, 33); STEP2B(sE, x20, x21, "2", "8");
        ISSUE_B8(sE, baddr); baddr += 640u; ISSUE_A(x20, x21, ap1, 34); STEP2B(sO, y20, y21, "2", "8");
        ISSUE_B8(sO, baddr); baddr += 640u; ISSUE_A(y20, y21, ap1, 35); STEP2B(sE, x20, x21, "2", "8");
        ISSUE_B8(sE, baddr); baddr += 640u; ISSUE_A(x20, x21, ap1, 36); STEP2B(sO, y20, y21, "2", "8");
        ISSUE_B8(sO, baddr); baddr += 640u; ISSUE_A(y20, y21, ap1, 37); STEP2B(sE, x20, x21, "2", "8");
        ISSUE_B8(sE, baddr); baddr += 640u; ISSUE_A(x20, x21, ap1, 38); STEP2B(sO, y20, y21, "2", "8");
        STEP2B(sE, x20, x21, "0", "0");

        asm volatile("s_waitcnt vmcnt(0) lgkmcnt(0)" ::: "memory");
    }

    float bv0 = 0.f, bv1 = 0.f, bv2 = 0.f, bv3 = 0.f;
    if (ADD_BIAS) { bv0 = bias[0]; bv1 = bias[1]; bv2 = bias[2]; bv3 = bias[3]; }

    #pragma unroll
    for (int j = 0; j < 2; j++) {
        int ox = x0 + xs + 32*j + (l & 31);
        if (ox > 352) continue;
        int px = ox + 15;
        #pragma unroll
        for (int rgi = 0; rgi < 16; rgi++) {
            int m  = rgi & 3;
            int dy = 2*(rgi >> 2) + hi;
            float v1 = (j == 0 ? q0[rgi] : q1[rgi]);
            float v2 = (j == 0 ? u0[rgi] : u1[rgi]);
            float bb = (m == 0 ? bv0 : m == 1 ? bv1 : m == 2 ? bv2 : bv3);
            int oy1 = yv + rg + dy;
            if (oy1 <= 352) {
                size_t o = ((size_t)(b*4 + m))*HW + (size_t)(oy1 + 15)*HH + px;
                float v = v1 + (ADD_BIAS ? bb : 0.f);
                if constexpr (OUT_BF16) ((bf16*)outp)[o] = f2b(v);
                else                    ((float*)outp)[o] = v;
            }
            int oy2 = yv + rg + 8 + dy;
            if (oy2 <= 352) {
                size_t o = ((size_t)(b*4 + m))*HW + (size_t)(oy2 + 15)*HH + px;
                float v = v2 + (ADD_BIAS ? bb : 0.f);
                if constexpr (OUT_BF16) ((bf16*)outp)[o] = f2b(v);
                else                    ((float*)outp)[o] = v;
            }
        }
    }
}

extern "C" void kernel_launch(void* const* d_in, const int* in_sizes, int n_in,
                              void* d_out, int out_size, void* d_ws, size_t ws_size,
                              hipStream_t stream)
{
    const float* inputs = (const float*)d_in[0];
    const float* fm     = (const float*)d_in[1];
    const float* meta   = (const float*)d_in[2];
    const float* mcw    = (const float*)d_in[3];
    const float* mcb    = (const float*)d_in[4];
    const float* mlw    = (const float*)d_in[5];
    const float* mlb    = (const float*)d_in[6];
    const float* icw    = (const float*)d_in[7];
    const float* icb    = (const float*)d_in[8];
    const float* bbw    = (const float*)d_in[9];
    const float* bbb    = (const float*)d_in[10];

    // workspace layout (bytes):
    //   ci     bf16 [32,4,384,384]      @ 0           37,748,736
    //   mapped bf16 [32,4,384,384]      @ 37,748,736  37,748,736
    //   wts    bf16 [32,16,1024]        @ 77,594,624   1,048,576
    //   atab1F bf16 [32,4,39,2,64,8]    @ 78,643,200  10,223,616
    //   atab2F bf16 [4,39,2,64,8]       @ 88,866,816     319,488
    //   part   f32  [32,2,16,1024]      @ 89,186,304   4,194,304  (own slot; bz16 runs
    //          concurrently with convfeats in fused_pre, so no overlay on mapped)
    char* ws = (char*)d_ws;
    bf16*   ci     = (bf16*) ws;
    bf16*   mapped = (bf16*)(ws + 37748736);
    bf16*   wts    = (bf16*)(ws + 77594624);
    ushort* atab1F = (ushort*)(ws + 78643200);
    ushort* atab2F = (ushort*)(ws + 88866816);
    float*  part   = (float*)(ws + 89186304);

    fused_pre<<<FUSED_GRID, 256, 0, stream>>>(inputs, icw, icb, ci,
                                              fm, mcw, part,
                                              bbw, atab2F,
                                              (ushort*)mapped, (float*)d_out);
    wts_kernel<<<512, 256, 0, stream>>>(meta, mlw, mlb, part, mcb, wts);
    atab1F_kernel<<<2496, 256, 0, stream>>>((const ushort*)wts, atab1F);

    conv32_duo<true, true, false><<<1152, 256, 0, stream>>>(
        (const ushort*)ci, atab1F, nullptr, mapped);

    conv32_duo<false, false, true><<<1152, 256, 0, stream>>>(
        (const ushort*)mapped, atab2F, bbb, d_out);
}

// Round 21
// 410.879 us; speedup vs baseline: 1.1490x; 1.0001x over previous
//
#include <hip/hip_runtime.h>
#include <hip/hip_bf16.h>

typedef __hip_bfloat16 bf16;
typedef __attribute__((ext_vector_type(8))) short short8_t;
typedef __attribute__((ext_vector_type(16))) float f32x16;
typedef __attribute__((ext_vector_type(2))) unsigned int uint2v;

#define HH 384
#define HW (384*384)
#define TOT_ELEMS (32u*4u*147456u)
#define NBORD 22847   // 384*384 - 353*353

// fused_pre block ranges
#define CI_END   18432
#define CF_END   (CI_END + 256)
#define AT2_END  (CF_END + 78)
#define BZ16_END (AT2_END + 11424)
#define BZ32_END (BZ16_END + 11424)
#define AT1Z_END (BZ32_END + 2496)     // zero atab1F: 638,976 uint4 / 256
#define FUSED_GRID AT1Z_END

__device__ inline float b2f(bf16 v){ return __bfloat162float(v); }
__device__ inline bf16  f2b(float v){ return __float2bfloat16(v); }
__device__ inline float sigm(float x){ return 1.f/(1.f+__expf(-x)); }

__device__ inline uint ab2(uint h, uint l){ return __builtin_amdgcn_alignbyte(h, l, 2); }

__device__ inline short8_t mk8p(uint2v a, uint2v b){
    union { uint u[4]; short8_t s; } t;
    t.u[0]=a[0]; t.u[1]=a[1]; t.u[2]=b[0]; t.u[3]=b[1]; return t.s;
}

// ======== fused prologue: ci | convfeats_part | atab2F | bz16 | bz32 | zero(atab1F) ========
__global__ __launch_bounds__(256) void fused_pre(const float* __restrict__ in,
                                                 const float* __restrict__ icw,
                                                 const float* __restrict__ icb,
                                                 bf16* __restrict__ ci,
                                                 const float* __restrict__ fm,
                                                 const float* __restrict__ mcw,
                                                 float* __restrict__ part,
                                                 const float* __restrict__ bbw,
                                                 ushort* __restrict__ atab2F,
                                                 ushort* __restrict__ mapped_bz,
                                                 float* __restrict__ out_bz,
                                                 uint4* __restrict__ atab1F_z)
{
    __shared__ float fsm[2048];
    int tid = threadIdx.x;
    int bx = blockIdx.x;

    if (bx < CI_END) {
        float* sw = fsm;          // 108
        float* sb = fsm + 108;    // 4
        if (tid < 108) sw[tid] = icw[tid];
        if (tid < 4)   sb[tid] = icb[tid];
        __syncthreads();
        size_t idx = (size_t)bx * 256 + tid;
        int x = (int)(idx % HH);
        int y = (int)((idx / HH) % HH);
        int b = (int)(idx / ((size_t)HH * HH));
        float v[4];
        if (y > 0 && y < HH-1 && x > 0 && x < HH-1) {
            float a0 = sb[0], a1 = sb[1], a2 = sb[2], a3 = sb[3];
            for (int ic = 0; ic < 3; ic++) {
                #pragma unroll
                for (int dy = 0; dy < 3; dy++) {
                    #pragma unroll
                    for (int dx = 0; dx < 3; dx++) {
                        float iv = in[((size_t)(b*3+ic)*HH + (y-1+dy))*HH + (x-1+dx)];
                        a0 = fmaf(iv, sw[0*27 + ic*9 + dy*3 + dx], a0);
                        a1 = fmaf(iv, sw[1*27 + ic*9 + dy*3 + dx], a1);
                        a2 = fmaf(iv, sw[2*27 + ic*9 + dy*3 + dx], a2);
                        a3 = fmaf(iv, sw[3*27 + ic*9 + dy*3 + dx], a3);
                    }
                }
            }
            v[0]=sigm(a0); v[1]=sigm(a1); v[2]=sigm(a2); v[3]=sigm(a3);
        } else {
            v[0]=v[1]=v[2]=v[3]=0.5f;
        }
        #pragma unroll
        for (int o = 0; o < 4; o++)
            ci[((size_t)(b*4+o)*HH + y)*HH + x] = f2b(v[o]);
        return;
    }
    if (bx < CF_END) {
        int bb = bx - CI_END;
        int b = bb >> 3;
        int rem = bb & 7;
        int chunk = rem >> 1, half = rem & 1;
        float* sw = fsm;   // [cl][k], 2048
        for (int i = tid; i < 2048; i += 256) {
            int k = i >> 7, cl = i & 127;
            sw[cl*16 + k] = mcw[k*256 + half*128 + cl];
        }
        __syncthreads();
        int hw = chunk*256 + tid;
        float acc[16];
        #pragma unroll
        for (int k = 0; k < 16; k++) acc[k] = 0.f;
        const float* f = fm + (size_t)b*256*1024 + (size_t)(half*128)*1024 + hw;
        for (int cl = 0; cl < 128; cl++) {
            float v = f[(size_t)cl*1024];
            const float4* wp = (const float4*)(sw + cl*16);
            #pragma unroll
            for (int q = 0; q < 4; q++) {
                float4 t = wp[q];
                acc[q*4+0] = fmaf(v, t.x, acc[q*4+0]);
                acc[q*4+1] = fmaf(v, t.y, acc[q*4+1]);
                acc[q*4+2] = fmaf(v, t.z, acc[q*4+2]);
                acc[q*4+3] = fmaf(v, t.w, acc[q*4+3]);
            }
        }
        #pragma unroll
        for (int k = 0; k < 16; k++)
            part[(size_t)(b*2 + half)*16384 + k*1024 + hw] = acc[k];
        return;
    }
    if (bx < AT2_END) {
        int g = (bx - CF_END)*256 + tid;
        if (g >= 4*39*2*64) return;
        int lane = g & 63, half = (g >> 6) & 1;
        int rest = g >> 7;
        int kyp = rest % 39;
        int c = rest / 39;
        int r = lane & 31, hi = lane >> 5;
        int dyA = r >> 2, mA = r & 3;
        int ch = mA*4 + c, ky = kyp - dyA, kx = 16*half + 8*hi;
        ushort v[8];
        if (ky >= 0 && ky < 32) {
            const float* src = bbw + (size_t)ch*1024 + ky*32 + kx;
            #pragma unroll
            for (int i=0;i<8;i++) { bf16 t = f2b(src[i]); v[i] = *(ushort*)&t; }
        } else {
            #pragma unroll
            for (int i=0;i<8;i++) v[i] = 0;
        }
        __builtin_memcpy(atab2F + (size_t)g*8, v, 16);
        return;
    }
    if (bx < BZ16_END) {
        int g = (bx - AT2_END)*256 + tid;
        if (g >= NBORD*128) return;
        int i = g % NBORD, bc = g / NBORD;
        int y, x;
        if (i < 11904) { int r = i / 384; y = (r < 15) ? r : 353 + r; x = i % 384; }
        else { int j = i - 11904; y = 15 + j / 31; int cc = j % 31; x = (cc < 15) ? cc : 353 + cc; }
        mapped_bz[(size_t)bc*HW + (size_t)y*HH + x] = 0;
        return;
    }
    if (bx < BZ32_END) {
        int g = (bx - BZ16_END)*256 + tid;
        if (g >= NBORD*128) return;
        int i = g % NBORD, bc = g / NBORD;
        int y, x;
        if (i < 11904) { int r = i / 384; y = (r < 15) ? r : 353 + r; x = i % 384; }
        else { int j = i - 11904; y = 15 + j / 31; int cc = j % 31; x = (cc < 15) ? cc : 353 + cc; }
        out_bz[(size_t)bc*HW + (size_t)y*HH + x] = 0.f;
        return;
    }
    {
        // zero atab1F (pad rows stay 0; valid entries overwritten by wts_atab next dispatch)
        int g = (bx - BZ32_END)*256 + tid;     // 638,976 uint4
        atab1F_z[g] = make_uint4(0u, 0u, 0u, 0u);
    }
}

// ---- wts+atab fused: compute sigmoid weights and scatter directly in MFMA lane order ----
// atab1F[(((b*4+c)*39 + (ky+dyA))*2 + half)*64 + hi*32 + dyA*4 + mA][j], dyA = 0..7
__global__ __launch_bounds__(256) void wts_atab_kernel(const float* __restrict__ meta,
                                                       const float* __restrict__ mlw,
                                                       const float* __restrict__ mlb,
                                                       const float* __restrict__ part,
                                                       const float* __restrict__ mcb,
                                                       ushort* __restrict__ atab1F)
{
    __shared__ float sm[64];
    __shared__ float sA[1024];
    __shared__ float sB[1024];
    int tid = threadIdx.x;
    int b = blockIdx.x >> 4, k = blockIdx.x & 15;
    if (tid < 64) sm[tid] = meta[(size_t)b*16*64 + k*64 + tid];
    float bk = mcb[k];
    #pragma unroll
    for (int q = 0; q < 4; q++) {
        int hw = q*256 + tid;
        sA[hw] = part[(size_t)(b*2 + 0)*16384 + k*1024 + hw]
               + part[(size_t)(b*2 + 1)*16384 + k*1024 + hw] + bk;
    }
    __syncthreads();
    #pragma unroll
    for (int q = 0; q < 4; q++) {
        int hw = q*256 + tid;
        const float4* wr = (const float4*)(mlw + (size_t)hw*64);
        float a = mlb[hw];
        #pragma unroll
        for (int d4 = 0; d4 < 16; d4++) {
            float4 t = wr[d4];
            a = fmaf(t.x, sm[d4*4+0], a);
            a = fmaf(t.y, sm[d4*4+1], a);
            a = fmaf(t.z, sm[d4*4+2], a);
            a = fmaf(t.w, sm[d4*4+3], a);
        }
        sB[hw] = a;
    }
    __syncthreads();
    int mA = k >> 2, c = k & 3;
    #pragma unroll
    for (int q = 0; q < 4; q++) {
        int il = q*256 + tid;
        int ky = il >> 5, kx = il & 31;
        float a = 0.f;
        #pragma unroll
        for (int j = 0; j < 32; j++)
            a = fmaf(sA[ky*32 + j], sB[j*32 + kx], a);
        bf16 bv = f2b(sigm(a));
        ushort uv = *(ushort*)&bv;
        int half = (kx >> 4) & 1, hi = (kx >> 3) & 1, jj = kx & 7;
        size_t addr0 = ((((size_t)(b*4 + c)*39 + ky)*2 + half)*64 + (hi*32 + mA))*8 + jj;
        #pragma unroll
        for (int d = 0; d < 8; d++)
            atab1F[addr0 + (size_t)d*1056] = uv;   // dyA: kyp+1 (+128g) & lane+4 (+4g) -> 132g*8
    }
}

// ================= duo-tile conv (r15, proven): 64-col waves, 3 waves/SIMD =================
// Wave: 16 out rows x 64 cols (T1 rows +0..7, T2 +8..15; 2 col strips). Block = 4 waves
// = 2 row-groups (0/16) x 2 x-strips (0/64) -> 32 rows x 128 cols. 47 steps/channel.
// LDS: 63 rows x 160 words (copy0 80 | copy1 80, bank-shift 16) = 40,320 B -> 3 blocks/CU.
// NO setprio (r14/r15 A/B: corrupts).
#define G_LOADX4(dst, addr, OFF) \
    asm volatile("global_load_dwordx4 %0, %1, off offset:" OFF : "=v"(dst) : "v"(addr))

#define ISSUE_A(A0_, A1_, ap_, e_)                                   \
{                                                                    \
    const ushort* p_ = (ap_) + (unsigned)(e_)*1024u;                 \
    G_LOADX4(A0_, p_, "0");                                          \
    G_LOADX4(A1_, p_, "1024");                                       \
}

#define ISSUE_B8(S, ADDR)                                                    \
    asm volatile(                                                            \
        "ds_read2_b32 %0, %8 offset0:0 offset1:1\n\t"                        \
        "ds_read2_b32 %1, %8 offset0:2 offset1:3\n\t"                        \
        "ds_read2_b32 %2, %8 offset0:8 offset1:9\n\t"                        \
        "ds_read2_b32 %3, %8 offset0:10 offset1:11\n\t"                      \
        "ds_read2_b32 %4, %8 offset0:16 offset1:17\n\t"                      \
        "ds_read2_b32 %5, %8 offset0:18 offset1:19\n\t"                      \
        "ds_read2_b32 %6, %8 offset0:24 offset1:25\n\t"                      \
        "ds_read2_b32 %7, %8 offset0:26 offset1:27"                          \
        : "=v"(S[0]), "=v"(S[1]), "=v"(S[2]), "=v"(S[3]), "=v"(S[4]),        \
          "=v"(S[5]), "=v"(S[6]), "=v"(S[7])                                 \
        : "v"(ADDR) : "memory")

#define KWAIT(VN, LN) do {                                                      \
    asm volatile("s_waitcnt vmcnt(" VN ") lgkmcnt(" LN ")" ::: "memory");       \
    __builtin_amdgcn_sched_barrier(0); } while (0)

#define MMp(acc_, A_, Pa, Pb) \
    acc_ = __builtin_amdgcn_mfma_f32_32x32x16_bf16(A_, mk8p(Pa, Pb), acc_, 0, 0, 0)

// T1-only: 4 MFMA (2 strips x 2 K-halves), same-acc distance 2
#define STEP1B(S, A0_, A1_, VN, LN) { KWAIT(VN, LN);                          \
    MMp(q0, A0_, S[0], S[1]);  MMp(q1, A0_, S[4], S[5]);                      \
    MMp(q0, A1_, S[2], S[3]);  MMp(q1, A1_, S[6], S[7]); }

#define STEP2B(S, C0_, C1_, VN, LN) { KWAIT(VN, LN);                          \
    MMp(u0, C0_, S[0], S[1]);  MMp(u1, C0_, S[4], S[5]);                      \
    MMp(u0, C1_, S[2], S[3]);  MMp(u1, C1_, S[6], S[7]); }

// both tiles: 8 MFMA, same-acc distance 4; q/u pairs share a B quad
#define STEP12B(S, A0_, A1_, C0_, C1_, VN, LN) { KWAIT(VN, LN);               \
    MMp(q0, A0_, S[0], S[1]);   MMp(u0, C0_, S[0], S[1]);                     \
    MMp(q1, A0_, S[4], S[5]);   MMp(u1, C0_, S[4], S[5]);                     \
    MMp(q0, A1_, S[2], S[3]);   MMp(u0, C1_, S[2], S[3]);                     \
    MMp(q1, A1_, S[6], S[7]);   MMp(u1, C1_, S[6], S[7]); }

template<bool PER_B, bool OUT_BF16, bool ADD_BIAS>
__global__ __launch_bounds__(256, 3) void conv32_duo(const ushort* __restrict__ in,
                                                     const ushort* __restrict__ atabF,
                                                     const float* __restrict__ bias,
                                                     void* __restrict__ outp)
{
    __shared__ uint sbuf[63*160];   // 40,320 B

    // XCD-chunk swizzle (1152 % 8 == 0)
    int d = blockIdx.x;
    int L = (d & 7) * 144 + (d >> 3);
    int b = L / 36; int rem = L % 36;
    int yb = rem / 3, xb = rem % 3;
    int yv = yb * 32;
    int x0 = xb * 128;

    int tid = threadIdx.x;
    int l = tid & 63, w = tid >> 6;
    int rg = (w >> 1) * 16;            // row-group 0 / 16
    int xs = (w & 1) * 64;             // local x start within 128-col block
    int hi = l >> 5;

    int s = xs + (l & 31) + 8*hi;      // local start element (0..103)
    int p = s & 1;
    const uint* swl = sbuf + (unsigned)(rg*160) + (unsigned)(p*80 + ((s - p) >> 1));
    uint baddr0 = (uint)(size_t)(const void*)swl;   // LDS byte offset

    f32x16 q0, q1, u0, u1;
    #pragma unroll
    for (int i = 0; i < 16; i++) { q0[i]=0.f; q1[i]=0.f; u0[i]=0.f; u1[i]=0.f; }

    unsigned chbase0 = (unsigned)b*589824u + (unsigned)yv*384u + (unsigned)x0;

    for (int c = 0; c < 4; ++c) {
        if (c) __syncthreads();
        // ---- stage channel c: local rows 0..62 (image rows yv..yv+62), 160 el + parity copy ----
        unsigned chb = chbase0 + (unsigned)c*147456u;
        for (int qq = tid; qq < 1260; qq += 256) {     // 63 rows * 20 chunks of 8 el
            int row = qq / 20, k = qq - row*20;
            unsigned gi = chb + (unsigned)row*384u + (unsigned)k*8u;
            if (gi > TOT_ELEMS - 16u) gi = TOT_ELEMS - 16u;
            const uint* gp = (const uint*)(in + gi);   // 16B aligned
            uint d0 = gp[0], d1 = gp[1], d2 = gp[2], d3 = gp[3], d4 = gp[4];
            unsigned widx = (unsigned)row*160u + (unsigned)k*4u;
            uint4* w0 = (uint4*)&sbuf[widx];
            uint4* w1 = (uint4*)&sbuf[widx + 80u];
            *w0 = make_uint4(d0, d1, d2, d3);
            *w1 = make_uint4(ab2(d1,d0), ab2(d2,d1), ab2(d3,d2), ab2(d4,d3));
        }
        __syncthreads();

        const ushort* ap1 = atabF + (size_t)((PER_B ? (b*4 + c) : c) * 39) * 1024 + l*8;
        short8_t xA0, xA1, x20, x21;      // A sets
        short8_t yA0, yA1, y20, y21;
        uint2v sE[8], sO[8];              // B double buffer
        uint baddr = baddr0;

        ISSUE_B8(sE, baddr); baddr += 640u;
        ISSUE_A(xA0, xA1, ap1, 0);

        // ---- P1: steps 0..7, T1 only ----
        ISSUE_B8(sO, baddr); baddr += 640u;
        ISSUE_A(yA0, yA1, ap1, 1);
        STEP1B(sE, xA0, xA1, "2", "8");
        ISSUE_B8(sE, baddr); baddr += 640u;
        ISSUE_A(xA0, xA1, ap1, 2);
        STEP1B(sO, yA0, yA1, "2", "8");
        ISSUE_B8(sO, baddr); baddr += 640u;
        ISSUE_A(yA0, yA1, ap1, 3);
        STEP1B(sE, xA0, xA1, "2", "8");
        ISSUE_B8(sE, baddr); baddr += 640u;
        ISSUE_A(xA0, xA1, ap1, 4);
        STEP1B(sO, yA0, yA1, "2", "8");
        ISSUE_B8(sO, baddr); baddr += 640u;
        ISSUE_A(yA0, yA1, ap1, 5);
        STEP1B(sE, xA0, xA1, "2", "8");
        ISSUE_B8(sE, baddr); baddr += 640u;
        ISSUE_A(xA0, xA1, ap1, 6);
        STEP1B(sO, yA0, yA1, "2", "8");
        ISSUE_B8(sO, baddr); baddr += 640u;
        ISSUE_A(yA0, yA1, ap1, 7);
        STEP1B(sE, xA0, xA1, "2", "8");
        ISSUE_B8(sE, baddr); baddr += 640u;
        ISSUE_A(xA0, xA1, ap1, 8);
        ISSUE_A(x20, x21, ap1, 0);
        STEP1B(sO, yA0, yA1, "4", "8");

        // ---- P2: steps 8..37, both tiles (T1 entry r, T2 entry r-8) ----
        #pragma unroll 1
        for (int t = 0; t < 15; ++t) {
            int r = 8 + 2*t;
            ISSUE_B8(sO, baddr); baddr += 640u;
            ISSUE_A(yA0, yA1, ap1, r+1); ISSUE_A(y20, y21, ap1, r-7);
            STEP12B(sE, xA0, xA1, x20, x21, "4", "8");
            ISSUE_B8(sE, baddr); baddr += 640u;
            ISSUE_A(xA0, xA1, ap1, r+2); ISSUE_A(x20, x21, ap1, r-6);
            STEP12B(sO, yA0, yA1, y20, y21, "4", "8");
        }
        // ---- step 38 ----
        ISSUE_B8(sO, baddr); baddr += 640u;
        ISSUE_A(y20, y21, ap1, 31);
        STEP12B(sE, xA0, xA1, x20, x21, "2", "8");

        // ---- P3: steps 39..46, T2 only (entries 31..38) ----
        ISSUE_B8(sE, baddr); baddr += 640u; ISSUE_A(x20, x21, ap1, 32); STEP2B(sO, y20, y21, "2", "8");
        ISSUE_B8(sO, baddr); baddr += 640u; ISSUE_A(y20, y21, ap1, 33); STEP2B(sE, x20, x21, "2", "8");
        ISSUE_B8(sE, baddr); baddr += 640u; ISSUE_A(x20, x21, ap1, 34); STEP2B(sO, y20, y21, "2", "8");
        ISSUE_B8(sO, baddr); baddr += 640u; ISSUE_A(y20, y21, ap1, 35); STEP2B(sE, x20, x21, "2", "8");
        ISSUE_B8(sE, baddr); baddr += 640u; ISSUE_A(x20, x21, ap1, 36); STEP2B(sO, y20, y21, "2", "8");
        ISSUE_B8(sO, baddr); baddr += 640u; ISSUE_A(y20, y21, ap1, 37); STEP2B(sE, x20, x21, "2", "8");
        ISSUE_B8(sE, baddr); baddr += 640u; ISSUE_A(x20, x21, ap1, 38); STEP2B(sO, y20, y21, "2", "8");
        STEP2B(sE, x20, x21, "0", "0");

        asm volatile("s_waitcnt vmcnt(0) lgkmcnt(0)" ::: "memory");
    }

    float bv0 = 0.f, bv1 = 0.f, bv2 = 0.f, bv3 = 0.f;
    if (ADD_BIAS) { bv0 = bias[0]; bv1 = bias[1]; bv2 = bias[2]; bv3 = bias[3]; }

    #pragma unroll
    for (int j = 0; j < 2; j++) {
        int ox = x0 + xs + 32*j + (l & 31);
        if (ox > 352) continue;
        int px = ox + 15;
        #pragma unroll
        for (int rgi = 0; rgi < 16; rgi++) {
            int m  = rgi & 3;
            int dy = 2*(rgi >> 2) + hi;
            float v1 = (j == 0 ? q0[rgi] : q1[rgi]);
            float v2 = (j == 0 ? u0[rgi] : u1[rgi]);
            float bb = (m == 0 ? bv0 : m == 1 ? bv1 : m == 2 ? bv2 : bv3);
            int oy1 = yv + rg + dy;
            if (oy1 <= 352) {
                size_t o = ((size_t)(b*4 + m))*HW + (size_t)(oy1 + 15)*HH + px;
                float v = v1 + (ADD_BIAS ? bb : 0.f);
                if constexpr (OUT_BF16) ((bf16*)outp)[o] = f2b(v);
                else                    ((float*)outp)[o] = v;
            }
            int oy2 = yv + rg + 8 + dy;
            if (oy2 <= 352) {
                size_t o = ((size_t)(b*4 + m))*HW + (size_t)(oy2 + 15)*HH + px;
                float v = v2 + (ADD_BIAS ? bb : 0.f);
                if constexpr (OUT_BF16) ((bf16*)outp)[o] = f2b(v);
                else                    ((float*)outp)[o] = v;
            }
        }
    }
}

extern "C" void kernel_launch(void* const* d_in, const int* in_sizes, int n_in,
                              void* d_out, int out_size, void* d_ws, size_t ws_size,
                              hipStream_t stream)
{
    const float* inputs = (const float*)d_in[0];
    const float* fm     = (const float*)d_in[1];
    const float* meta   = (const float*)d_in[2];
    const float* mcw    = (const float*)d_in[3];
    const float* mcb    = (const float*)d_in[4];
    const float* mlw    = (const float*)d_in[5];
    const float* mlb    = (const float*)d_in[6];
    const float* icw    = (const float*)d_in[7];
    const float* icb    = (const float*)d_in[8];
    const float* bbw    = (const float*)d_in[9];
    const float* bbb    = (const float*)d_in[10];

    // workspace layout (bytes):
    //   ci     bf16 [32,4,384,384]      @ 0           37,748,736
    //   mapped bf16 [32,4,384,384]      @ 37,748,736  37,748,736
    //   atab1F bf16 [32,4,39,2,64,8]    @ 78,643,200  10,223,616
    //   atab2F bf16 [4,39,2,64,8]       @ 88,866,816     319,488
    //   part   f32  [32,2,16,1024]      @ 89,186,304   4,194,304
    char* ws = (char*)d_ws;
    bf16*   ci     = (bf16*) ws;
    bf16*   mapped = (bf16*)(ws + 37748736);
    ushort* atab1F = (ushort*)(ws + 78643200);
    ushort* atab2F = (ushort*)(ws + 88866816);
    float*  part   = (float*)(ws + 89186304);

    fused_pre<<<FUSED_GRID, 256, 0, stream>>>(inputs, icw, icb, ci,
                                              fm, mcw, part,
                                              bbw, atab2F,
                                              (ushort*)mapped, (float*)d_out,
                                              (uint4*)atab1F);
    wts_atab_kernel<<<512, 256, 0, stream>>>(meta, mlw, mlb, part, mcb, atab1F);

    conv32_duo<true, true, false><<<1152, 256, 0, stream>>>(
        (const ushort*)ci, atab1F, nullptr, mapped);

    conv32_duo<false, false, true><<<1152, 256, 0, stream>>>(
        (const ushort*)mapped, atab2F, bbb, d_out);
}